// Round 1
// baseline (252.458 us; speedup 1.0000x reference)
//
#include <hip/hip_runtime.h>
#include <hip/hip_bf16.h>
#include <cstddef>
#include <cstdint>

#define BS    8
#define M_PTS 1024
#define N_PTS 4096
#define C0    256
#define C1    128
#define C2    256
#define K1DIM 384   // C0 + C1

// ---------------------------------------------------------------------------
// Generic batched 32x32 tiled transpose: in (nb, R, C) -> out (nb, C, R)
// ---------------------------------------------------------------------------
__global__ void transpose_k(const float* __restrict__ in, float* __restrict__ out,
                            int R, int C) {
  __shared__ float tile[32][33];
  const int b  = blockIdx.z;
  const int r0 = blockIdx.y * 32, c0 = blockIdx.x * 32;
  const int tx = threadIdx.x, ty = threadIdx.y;   // 32 x 8
  const float* ip = in  + (size_t)b * R * C;
  float*       op = out + (size_t)b * R * C;
#pragma unroll
  for (int i = 0; i < 4; ++i) {
    int r = r0 + ty + i * 8, c = c0 + tx;
    if (r < R && c < C) tile[ty + i * 8][tx] = ip[(size_t)r * C + c];
  }
  __syncthreads();
#pragma unroll
  for (int i = 0; i < 4; ++i) {
    int c = c0 + ty + i * 8, r = r0 + tx;
    if (r < R && c < C) op[(size_t)c * R + r] = tile[tx][ty + i * 8];
  }
}

// ---------------------------------------------------------------------------
// three_nn: for each query find 3 nearest reference points (squared-dist
// formula mirrors the reference: |q|^2 - 2 q.x + |x|^2, no FMA contraction).
// 4 sub-threads per query, each scans 256 points in index order; staggered
// LDS layout (pos = m + (m>>8)) keeps the 4 sub-streams on distinct banks.
// ---------------------------------------------------------------------------
__global__ __launch_bounds__(256) void three_nn_k(
    const float* __restrict__ xyz, const float* __restrict__ pxyz,
    int* __restrict__ idx_o, float* __restrict__ w_o) {
  __shared__ float sx[1028], sy[1028], sz[1028], s2[1028];
  __shared__ float md[64][4][3];
  __shared__ int   mi[64][4][3];
  const int t  = threadIdx.x;
  const int b  = blockIdx.x >> 6;           // 64 blocks per batch
  const int q0 = (blockIdx.x & 63) * 64;    // 64 queries per block

  for (int i = t; i < 3 * M_PTS; i += 256) {
    float v = xyz[(size_t)b * 3 * M_PTS + i];
    int m = i / 3, k = i - 3 * m;
    int p = m + (m >> 8);
    if (k == 0) sx[p] = v; else if (k == 1) sy[p] = v; else sz[p] = v;
  }
  __syncthreads();
  for (int m = t; m < M_PTS; m += 256) {
    int p = m + (m >> 8);
    float x = sx[p], y = sy[p], z = sz[p];
    s2[p] = __fadd_rn(__fadd_rn(__fmul_rn(x, x), __fmul_rn(y, y)), __fmul_rn(z, z));
  }
  __syncthreads();

  const int q = t >> 2, sub = t & 3;
  const int n = q0 + q;
  const float qx = pxyz[((size_t)b * N_PTS + n) * 3 + 0];
  const float qy = pxyz[((size_t)b * N_PTS + n) * 3 + 1];
  const float qz = pxyz[((size_t)b * N_PTS + n) * 3 + 2];
  const float qq = __fadd_rn(__fadd_rn(__fmul_rn(qx, qx), __fmul_rn(qy, qy)),
                             __fmul_rn(qz, qz));
  float d0 = 3.4e38f, d1 = 3.4e38f, d2 = 3.4e38f;
  int   i0 = 0, i1 = 0, i2 = 0;
  const int mbase = sub * 256;
  const int pbase = mbase + sub;            // padded base
  for (int it = 0; it < 256; ++it) {
    int p = pbase + it;
    float dot = __fadd_rn(__fadd_rn(__fmul_rn(qx, sx[p]), __fmul_rn(qy, sy[p])),
                          __fmul_rn(qz, sz[p]));
    float d = __fadd_rn(__fsub_rn(qq, __fmul_rn(2.0f, dot)), s2[p]);
    int m = mbase + it;
    if (d < d0)      { d2 = d1; i2 = i1; d1 = d0; i1 = i0; d0 = d; i0 = m; }
    else if (d < d1) { d2 = d1; i2 = i1; d1 = d;  i1 = m; }
    else if (d < d2) { d2 = d;  i2 = m; }
  }
  md[q][sub][0] = d0; md[q][sub][1] = d1; md[q][sub][2] = d2;
  mi[q][sub][0] = i0; mi[q][sub][1] = i1; mi[q][sub][2] = i2;
  __syncthreads();

  if (sub == 0) {
    float e0 = 3.4e38f, e1 = 3.4e38f, e2 = 3.4e38f;
    int   j0 = 0, j1 = 0, j2 = 0;
#pragma unroll
    for (int s = 0; s < 4; ++s)
#pragma unroll
      for (int k = 0; k < 3; ++k) {
        float d = md[q][s][k]; int m = mi[q][s][k];
        if (d < e0)      { e2 = e1; j2 = j1; e1 = e0; j1 = j0; e0 = d; j0 = m; }
        else if (d < e1) { e2 = e1; j2 = j1; e1 = d;  j1 = m; }
        else if (d < e2) { e2 = d;  j2 = m; }
      }
    float t0 = sqrtf(fmaxf(e0, 0.f)), t1 = sqrtf(fmaxf(e1, 0.f)),
          t2 = sqrtf(fmaxf(e2, 0.f));
    float r0 = 1.0f / (t0 + 1e-8f), r1 = 1.0f / (t1 + 1e-8f),
          r2 = 1.0f / (t2 + 1e-8f);
    float rs = __fadd_rn(__fadd_rn(r0, r1), r2);
    size_t base = ((size_t)b * N_PTS + n) * 3;
    idx_o[base + 0] = j0; idx_o[base + 1] = j1; idx_o[base + 2] = j2;
    w_o[base + 0] = r0 / rs; w_o[base + 1] = r1 / rs; w_o[base + 2] = r2 / rs;
  }
}

// ---------------------------------------------------------------------------
// Fused: interpolate -> concat -> conv1(ReLU) -> conv2(ReLU) for a 32-column
// tile. pfT is column-major [j][k] with stride 385 (== 1 mod 32): hot-loop
// b-reads pfT[4tx+cc][kk] land on 8 distinct banks with 8-lane broadcast.
// Weights stream from global (L1/L2-resident, shared across all blocks).
// ---------------------------------------------------------------------------
#define BN  32
#define PFP 385

__global__ __launch_bounds__(256) void fused_k(
    const float* __restrict__ featsT,   // (BS, M, C0)
    const float* __restrict__ skip,     // (BS, C1, N)
    const float* __restrict__ W1t,      // (K1DIM, C2)
    const float* __restrict__ b1,
    const float* __restrict__ W2t,      // (C2, C2)
    const float* __restrict__ b2,
    const int* __restrict__ idx3, const float* __restrict__ w3,
    float* __restrict__ out) {          // (BS, C2, N)
  __shared__ float pfT[BN][PFP];
  __shared__ int   idx_s[BN][3];
  __shared__ float w_s[BN][3];
  const int t  = threadIdx.x;
  const int b  = blockIdx.x >> 7;           // N/BN = 128 blocks per batch
  const int n0 = (blockIdx.x & 127) * BN;

  if (t < BN * 3) {
    int j = t / 3, k = t - 3 * (t / 3);
    size_t g = ((size_t)b * N_PTS + n0 + j) * 3 + k;
    idx_s[j][k] = idx3[g];
    w_s[j][k]   = w3[g];
  }
  __syncthreads();

  // --- build rows 0..255 (interpolated feats), written transposed ---
  {
    const int c4 = (t & 63) * 4;            // channel quad
    const int j0 = (t >> 6) * 8;            // 8 columns per thread-group
#pragma unroll
    for (int i = 0; i < 8; ++i) {
      int j = j0 + i;
      int a0 = idx_s[j][0], a1 = idx_s[j][1], a2 = idx_s[j][2];
      float w0 = w_s[j][0], w1 = w_s[j][1], w2 = w_s[j][2];
      const float4 f0 = *(const float4*)(featsT + ((size_t)b * M_PTS + a0) * C0 + c4);
      const float4 f1 = *(const float4*)(featsT + ((size_t)b * M_PTS + a1) * C0 + c4);
      const float4 f2 = *(const float4*)(featsT + ((size_t)b * M_PTS + a2) * C0 + c4);
      // scalar LDS stores (row stride 385 words is not 16B-aligned)
      pfT[j][c4 + 0] = w0 * f0.x + w1 * f1.x + w2 * f2.x;
      pfT[j][c4 + 1] = w0 * f0.y + w1 * f1.y + w2 * f2.y;
      pfT[j][c4 + 2] = w0 * f0.z + w1 * f1.z + w2 * f2.z;
      pfT[j][c4 + 3] = w0 * f0.w + w1 * f1.w + w2 * f2.w;
    }
  }
  // --- rows 256..383 (skip feats) ---
#pragma unroll
  for (int i = 0; i < 16; ++i) {
    int id = t + i * 256;
    int j = id & 31, r = id >> 5;
    pfT[j][C0 + r] = skip[((size_t)b * C1 + r) * N_PTS + n0 + j];
  }
  __syncthreads();

  const int tx4 = (t & 7) * 4;              // 4 columns
  const int ty8 = (t >> 3) * 8;             // 8 rows
  float acc[8][4];
#pragma unroll
  for (int i = 0; i < 8; ++i)
#pragma unroll
    for (int c = 0; c < 4; ++c) acc[i][c] = 0.f;

  // ---------------- GEMM1: 256x384 @ 384x32 ----------------
#pragma unroll 4
  for (int kk = 0; kk < K1DIM; ++kk) {
    const float4 a0 = *(const float4*)(W1t + (size_t)kk * C2 + ty8);
    const float4 a1 = *(const float4*)(W1t + (size_t)kk * C2 + ty8 + 4);
    float bb[4];
#pragma unroll
    for (int c = 0; c < 4; ++c) bb[c] = pfT[tx4 + c][kk];
    const float a[8] = {a0.x, a0.y, a0.z, a0.w, a1.x, a1.y, a1.z, a1.w};
#pragma unroll
    for (int i = 0; i < 8; ++i)
#pragma unroll
      for (int c = 0; c < 4; ++c) acc[i][c] = fmaf(a[i], bb[c], acc[i][c]);
  }
  __syncthreads();   // all pfT reads done

  // h = relu(acc + b1) -> pfT[j][row]
  {
    float bias[8];
#pragma unroll
    for (int i = 0; i < 8; ++i) bias[i] = b1[ty8 + i];
#pragma unroll
    for (int i = 0; i < 8; ++i)
#pragma unroll
      for (int c = 0; c < 4; ++c)
        pfT[tx4 + c][ty8 + i] = fmaxf(acc[i][c] + bias[i], 0.0f);
  }
  __syncthreads();

#pragma unroll
  for (int i = 0; i < 8; ++i)
#pragma unroll
    for (int c = 0; c < 4; ++c) acc[i][c] = 0.f;

  // ---------------- GEMM2: 256x256 @ 256x32 ----------------
#pragma unroll 4
  for (int kk = 0; kk < C2; ++kk) {
    const float4 a0 = *(const float4*)(W2t + (size_t)kk * C2 + ty8);
    const float4 a1 = *(const float4*)(W2t + (size_t)kk * C2 + ty8 + 4);
    float bb[4];
#pragma unroll
    for (int c = 0; c < 4; ++c) bb[c] = pfT[tx4 + c][kk];
    const float a[8] = {a0.x, a0.y, a0.z, a0.w, a1.x, a1.y, a1.z, a1.w};
#pragma unroll
    for (int i = 0; i < 8; ++i)
#pragma unroll
      for (int c = 0; c < 4; ++c) acc[i][c] = fmaf(a[i], bb[c], acc[i][c]);
  }

  // epilogue: relu(acc + b2) -> out, coalesced float4
  {
    float bias[8];
#pragma unroll
    for (int i = 0; i < 8; ++i) bias[i] = b2[ty8 + i];
#pragma unroll
    for (int i = 0; i < 8; ++i) {
      float4 v;
      v.x = fmaxf(acc[i][0] + bias[i], 0.f);
      v.y = fmaxf(acc[i][1] + bias[i], 0.f);
      v.z = fmaxf(acc[i][2] + bias[i], 0.f);
      v.w = fmaxf(acc[i][3] + bias[i], 0.f);
      *(float4*)(out + ((size_t)b * C2 + ty8 + i) * N_PTS + n0 + tx4) = v;
    }
  }
}

// ---------------------------------------------------------------------------
extern "C" void kernel_launch(void* const* d_in, const int* in_sizes, int n_in,
                              void* d_out, int out_size, void* d_ws, size_t ws_size,
                              hipStream_t stream) {
  const float* xyz   = (const float*)d_in[0];
  const float* pxyz  = (const float*)d_in[1];
  const float* feats = (const float*)d_in[2];
  const float* skip  = (const float*)d_in[3];
  const float* W1    = (const float*)d_in[4];
  const float* b1    = (const float*)d_in[5];
  const float* W2    = (const float*)d_in[6];
  const float* b2    = (const float*)d_in[7];
  float* out = (float*)d_out;

  float* ws     = (float*)d_ws;
  float* featsT = ws;                                   // 8*1024*256
  float* W1t    = featsT + (size_t)BS * M_PTS * C0;     // 384*256
  float* W2t    = W1t + (size_t)K1DIM * C2;             // 256*256
  int*   idx3   = (int*)(W2t + (size_t)C2 * C2);        // 8*4096*3
  float* w3     = (float*)(idx3 + (size_t)BS * N_PTS * 3);

  dim3 tb(32, 8);
  transpose_k<<<dim3(M_PTS / 32, C0 / 32, BS), tb, 0, stream>>>(feats, featsT, C0, M_PTS);
  transpose_k<<<dim3(K1DIM / 32, C2 / 32, 1), tb, 0, stream>>>(W1, W1t, C2, K1DIM);
  transpose_k<<<dim3(C2 / 32, C2 / 32, 1), tb, 0, stream>>>(W2, W2t, C2, C2);
  three_nn_k<<<BS * (N_PTS / 64), 256, 0, stream>>>(xyz, pxyz, idx3, w3);
  fused_k<<<BS * (N_PTS / BN), 256, 0, stream>>>(featsT, skip, W1t, b1, W2t, b2,
                                                 idx3, w3, out);
}

// Round 2
// 86.762 us; speedup vs baseline: 2.9098x; 2.9098x over previous
//
#include <hip/hip_runtime.h>
#include <hip/hip_bf16.h>
#include <cstddef>
#include <cstdint>

#define BS    8
#define M_PTS 1024
#define N_PTS 4096
#define C0    256
#define C1    128
#define C2    256
#define K1DIM 384   // C0 + C1

typedef __attribute__((ext_vector_type(8))) short bf16x8;
typedef __attribute__((ext_vector_type(4))) float f32x4;

__device__ __forceinline__ ushort f2bf(float f) {
  union { float f; unsigned u; } v; v.f = f;
  unsigned r = v.u + 0x7fffu + ((v.u >> 16) & 1u);   // RNE
  return (ushort)(r >> 16);
}

// ---------------------------------------------------------------------------
// Batched 32x32 tiled transpose: in (nb, R, C) -> out (nb, C, R)
// ---------------------------------------------------------------------------
__global__ void transpose_k(const float* __restrict__ in, float* __restrict__ out,
                            int R, int C) {
  __shared__ float tile[32][33];
  const int b  = blockIdx.z;
  const int r0 = blockIdx.y * 32, c0 = blockIdx.x * 32;
  const int tx = threadIdx.x, ty = threadIdx.y;   // 32 x 8
  const float* ip = in  + (size_t)b * R * C;
  float*       op = out + (size_t)b * R * C;
#pragma unroll
  for (int i = 0; i < 4; ++i) {
    int r = r0 + ty + i * 8, c = c0 + tx;
    if (r < R && c < C) tile[ty + i * 8][tx] = ip[(size_t)r * C + c];
  }
  __syncthreads();
#pragma unroll
  for (int i = 0; i < 4; ++i) {
    int c = c0 + ty + i * 8, r = r0 + tx;
    if (r < R && c < C) op[(size_t)c * R + r] = tile[tx][ty + i * 8];
  }
}

// ---------------------------------------------------------------------------
// Weight prep: f32 (c_out, c_in) row-major -> bf16 in MFMA A-fragment order
// [mb][kblk][g][r][e]  (m = mb*16+r, k = kblk*32+g*8+e)
// ---------------------------------------------------------------------------
__global__ __launch_bounds__(256) void wprep_k(
    const float* __restrict__ W1, const float* __restrict__ W2,
    ushort* __restrict__ W1f, ushort* __restrict__ W2f) {
  const int id = blockIdx.x * 256 + threadIdx.x;
  if (id < C2 * K1DIM) {
    int m = id / K1DIM, k = id - m * K1DIM;
    int off = (((m >> 4) * 12 + (k >> 5)) * 4 + ((k >> 3) & 3)) * 128 + (m & 15) * 8 + (k & 7);
    W1f[off] = f2bf(W1[id]);
  }
  if (id < C2 * C2) {
    int m = id >> 8, k = id & 255;
    int off = (((m >> 4) * 8 + (k >> 5)) * 4 + ((k >> 3) & 3)) * 128 + (m & 15) * 8 + (k & 7);
    W2f[off] = f2bf(W2[id]);
  }
}

// ---------------------------------------------------------------------------
// three_nn (unchanged from round 1 — exact match with reference top_k)
// ---------------------------------------------------------------------------
__global__ __launch_bounds__(256) void three_nn_k(
    const float* __restrict__ xyz, const float* __restrict__ pxyz,
    int* __restrict__ idx_o, float* __restrict__ w_o) {
  __shared__ float sx[1028], sy[1028], sz[1028], s2[1028];
  __shared__ float md[64][4][3];
  __shared__ int   mi[64][4][3];
  const int t  = threadIdx.x;
  const int b  = blockIdx.x >> 6;
  const int q0 = (blockIdx.x & 63) * 64;

  for (int i = t; i < 3 * M_PTS; i += 256) {
    float v = xyz[(size_t)b * 3 * M_PTS + i];
    int m = i / 3, k = i - 3 * m;
    int p = m + (m >> 8);
    if (k == 0) sx[p] = v; else if (k == 1) sy[p] = v; else sz[p] = v;
  }
  __syncthreads();
  for (int m = t; m < M_PTS; m += 256) {
    int p = m + (m >> 8);
    float x = sx[p], y = sy[p], z = sz[p];
    s2[p] = __fadd_rn(__fadd_rn(__fmul_rn(x, x), __fmul_rn(y, y)), __fmul_rn(z, z));
  }
  __syncthreads();

  const int q = t >> 2, sub = t & 3;
  const int n = q0 + q;
  const float qx = pxyz[((size_t)b * N_PTS + n) * 3 + 0];
  const float qy = pxyz[((size_t)b * N_PTS + n) * 3 + 1];
  const float qz = pxyz[((size_t)b * N_PTS + n) * 3 + 2];
  const float qq = __fadd_rn(__fadd_rn(__fmul_rn(qx, qx), __fmul_rn(qy, qy)),
                             __fmul_rn(qz, qz));
  float d0 = 3.4e38f, d1 = 3.4e38f, d2 = 3.4e38f;
  int   i0 = 0, i1 = 0, i2 = 0;
  const int mbase = sub * 256;
  const int pbase = mbase + sub;
  for (int it = 0; it < 256; ++it) {
    int p = pbase + it;
    float dot = __fadd_rn(__fadd_rn(__fmul_rn(qx, sx[p]), __fmul_rn(qy, sy[p])),
                          __fmul_rn(qz, sz[p]));
    float d = __fadd_rn(__fsub_rn(qq, __fmul_rn(2.0f, dot)), s2[p]);
    int m = mbase + it;
    if (d < d0)      { d2 = d1; i2 = i1; d1 = d0; i1 = i0; d0 = d; i0 = m; }
    else if (d < d1) { d2 = d1; i2 = i1; d1 = d;  i1 = m; }
    else if (d < d2) { d2 = d;  i2 = m; }
  }
  md[q][sub][0] = d0; md[q][sub][1] = d1; md[q][sub][2] = d2;
  mi[q][sub][0] = i0; mi[q][sub][1] = i1; mi[q][sub][2] = i2;
  __syncthreads();

  if (sub == 0) {
    float e0 = 3.4e38f, e1 = 3.4e38f, e2 = 3.4e38f;
    int   j0 = 0, j1 = 0, j2 = 0;
#pragma unroll
    for (int s = 0; s < 4; ++s)
#pragma unroll
      for (int k = 0; k < 3; ++k) {
        float d = md[q][s][k]; int m = mi[q][s][k];
        if (d < e0)      { e2 = e1; j2 = j1; e1 = e0; j1 = j0; e0 = d; j0 = m; }
        else if (d < e1) { e2 = e1; j2 = j1; e1 = d;  j1 = m; }
        else if (d < e2) { e2 = d;  j2 = m; }
      }
    float t0 = sqrtf(fmaxf(e0, 0.f)), t1 = sqrtf(fmaxf(e1, 0.f)),
          t2 = sqrtf(fmaxf(e2, 0.f));
    float r0 = 1.0f / (t0 + 1e-8f), r1 = 1.0f / (t1 + 1e-8f),
          r2 = 1.0f / (t2 + 1e-8f);
    float rs = __fadd_rn(__fadd_rn(r0, r1), r2);
    size_t base = ((size_t)b * N_PTS + n) * 3;
    idx_o[base + 0] = j0; idx_o[base + 1] = j1; idx_o[base + 2] = j2;
    w_o[base + 0] = r0 / rs; w_o[base + 1] = r1 / rs; w_o[base + 2] = r2 / rs;
  }
}

// ---------------------------------------------------------------------------
// Fused MFMA: interpolate -> concat -> conv1(ReLU) -> conv2(ReLU), 64-col tile.
// pfB holds the B operand in fragment order: ushort index (k>>3)*512 + n*8 + (k&7).
// A-frags stream from global bf16 weights (fragment order, fully coalesced).
// 4 waves, each owns 64 output rows x 64 cols = 16 16x16 fragments.
// ---------------------------------------------------------------------------
__global__ __launch_bounds__(256) void fused_mfma_k(
    const float* __restrict__ featsT,   // (BS, M, C0) f32
    const float* __restrict__ skip,     // (BS, C1, N) f32
    const ushort* __restrict__ W1f,     // frag-order bf16
    const float* __restrict__ b1,
    const ushort* __restrict__ W2f,     // frag-order bf16
    const float* __restrict__ b2,
    const int* __restrict__ idx3, const float* __restrict__ w3,
    float* __restrict__ out) {          // (BS, C2, N) f32
  __shared__ ushort pfB[24576];         // 48 KiB: K1DIM x 64 bf16, frag order
  __shared__ int   idx_s[64][3];
  __shared__ float w_s[64][3];
  const int t  = threadIdx.x;
  const int b  = blockIdx.x & 7;            // XCD-pinned batch
  const int n0 = (blockIdx.x >> 3) * 64;

  if (t < 192) {
    int j = t / 3, kk = t - 3 * (t / 3);
    size_t gg = ((size_t)b * N_PTS + n0 + j) * 3 + kk;
    idx_s[j][kk] = idx3[gg];
    w_s[j][kk]   = w3[gg];
  }
  __syncthreads();

  // ---- build rows 0..255: interpolated feats, bf16, frag order ----
  {
    const int n = t & 63, cg = t >> 6;
    const float w0 = w_s[n][0], w1 = w_s[n][1], w2 = w_s[n][2];
    const float* f0p = featsT + ((size_t)b * M_PTS + idx_s[n][0]) * C0;
    const float* f1p = featsT + ((size_t)b * M_PTS + idx_s[n][1]) * C0;
    const float* f2p = featsT + ((size_t)b * M_PTS + idx_s[n][2]) * C0;
#pragma unroll
    for (int q = 0; q < 16; ++q) {
      const int k0 = cg * 64 + q * 4;
      const float4 f0 = *(const float4*)(f0p + k0);
      const float4 f1 = *(const float4*)(f1p + k0);
      const float4 f2 = *(const float4*)(f2p + k0);
      ushort4 hv;
      hv.x = f2bf(w0 * f0.x + w1 * f1.x + w2 * f2.x);
      hv.y = f2bf(w0 * f0.y + w1 * f1.y + w2 * f2.y);
      hv.z = f2bf(w0 * f0.z + w1 * f1.z + w2 * f2.z);
      hv.w = f2bf(w0 * f0.w + w1 * f1.w + w2 * f2.w);
      *reinterpret_cast<ushort4*>(&pfB[(k0 >> 3) * 512 + n * 8 + (k0 & 7)]) = hv;
    }
    // ---- rows 256..383: skip feats ----
#pragma unroll
    for (int it = 0; it < 16; ++it) {
      const int id = t + it * 256;
      const int r2 = id >> 6, nn = id & 63;
      const int k = C0 + r2 * 2;
      const float s0v = skip[((size_t)b * C1 + 2 * r2 + 0) * N_PTS + n0 + nn];
      const float s1v = skip[((size_t)b * C1 + 2 * r2 + 1) * N_PTS + n0 + nn];
      ushort2 sv; sv.x = f2bf(s0v); sv.y = f2bf(s1v);
      *reinterpret_cast<ushort2*>(&pfB[(k >> 3) * 512 + nn * 8 + (k & 7)]) = sv;
    }
  }
  __syncthreads();

  const int w = t >> 6;             // wave: rows 64w..64w+63
  const int l = t & 63, c = l & 15, g = l >> 4;

  f32x4 acc[4][4];
#pragma unroll
  for (int i = 0; i < 4; ++i)
#pragma unroll
    for (int j = 0; j < 4; ++j) acc[i][j] = (f32x4){0.f, 0.f, 0.f, 0.f};

  // ---------------- GEMM1: h = relu(W1 @ pf + b1), K = 384 ----------------
  for (int kb = 0; kb < 12; ++kb) {
    bf16x8 bfr[4], afr[4];
#pragma unroll
    for (int j = 0; j < 4; ++j)
      bfr[j] = *reinterpret_cast<const bf16x8*>(&pfB[((kb * 4 + g) * 64 + j * 16 + c) * 8]);
#pragma unroll
    for (int i = 0; i < 4; ++i)
      afr[i] = *reinterpret_cast<const bf16x8*>(&W1f[(((4 * w + i) * 12 + kb) * 4 + g) * 128 + c * 8]);
#pragma unroll
    for (int i = 0; i < 4; ++i)
#pragma unroll
      for (int j = 0; j < 4; ++j)
        acc[i][j] = __builtin_amdgcn_mfma_f32_16x16x32_bf16(afr[i], bfr[j], acc[i][j], 0, 0, 0);
  }
  __syncthreads();                  // all pfB reads done before overwrite

  // h -> pfB (bf16, frag order). reg r of acc maps to m = mbase + r,
  // all 4 contiguous in e (mbase%8 is 0 or 4) -> packed ushort4 write.
#pragma unroll
  for (int i = 0; i < 4; ++i) {
    const int mbase = w * 64 + i * 16 + g * 4;
    const float4 bias = *(const float4*)(b1 + mbase);
#pragma unroll
    for (int j = 0; j < 4; ++j) {
      const int n = j * 16 + c;
      ushort4 hv;
      hv.x = f2bf(fmaxf(acc[i][j].x + bias.x, 0.f));
      hv.y = f2bf(fmaxf(acc[i][j].y + bias.y, 0.f));
      hv.z = f2bf(fmaxf(acc[i][j].z + bias.z, 0.f));
      hv.w = f2bf(fmaxf(acc[i][j].w + bias.w, 0.f));
      *reinterpret_cast<ushort4*>(&pfB[(mbase >> 3) * 512 + n * 8 + (mbase & 7)]) = hv;
    }
  }
  __syncthreads();

#pragma unroll
  for (int i = 0; i < 4; ++i)
#pragma unroll
    for (int j = 0; j < 4; ++j) acc[i][j] = (f32x4){0.f, 0.f, 0.f, 0.f};

  // ---------------- GEMM2: out = relu(W2 @ h + b2), K = 256 ----------------
  for (int kb = 0; kb < 8; ++kb) {
    bf16x8 bfr[4], afr[4];
#pragma unroll
    for (int j = 0; j < 4; ++j)
      bfr[j] = *reinterpret_cast<const bf16x8*>(&pfB[((kb * 4 + g) * 64 + j * 16 + c) * 8]);
#pragma unroll
    for (int i = 0; i < 4; ++i)
      afr[i] = *reinterpret_cast<const bf16x8*>(&W2f[(((4 * w + i) * 8 + kb) * 4 + g) * 128 + c * 8]);
#pragma unroll
    for (int i = 0; i < 4; ++i)
#pragma unroll
      for (int j = 0; j < 4; ++j)
        acc[i][j] = __builtin_amdgcn_mfma_f32_16x16x32_bf16(afr[i], bfr[j], acc[i][j], 0, 0, 0);
  }

  // epilogue: relu(acc + b2) -> out (coalesced across lane%16)
#pragma unroll
  for (int i = 0; i < 4; ++i) {
    const int mbase = w * 64 + i * 16 + g * 4;
    const float4 bias = *(const float4*)(b2 + mbase);
#pragma unroll
    for (int j = 0; j < 4; ++j) {
      const int n = n0 + j * 16 + c;
      out[((size_t)b * C2 + mbase + 0) * N_PTS + n] = fmaxf(acc[i][j].x + bias.x, 0.f);
      out[((size_t)b * C2 + mbase + 1) * N_PTS + n] = fmaxf(acc[i][j].y + bias.y, 0.f);
      out[((size_t)b * C2 + mbase + 2) * N_PTS + n] = fmaxf(acc[i][j].z + bias.z, 0.f);
      out[((size_t)b * C2 + mbase + 3) * N_PTS + n] = fmaxf(acc[i][j].w + bias.w, 0.f);
    }
  }
}

// ---------------------------------------------------------------------------
extern "C" void kernel_launch(void* const* d_in, const int* in_sizes, int n_in,
                              void* d_out, int out_size, void* d_ws, size_t ws_size,
                              hipStream_t stream) {
  const float* xyz   = (const float*)d_in[0];
  const float* pxyz  = (const float*)d_in[1];
  const float* feats = (const float*)d_in[2];
  const float* skip  = (const float*)d_in[3];
  const float* W1    = (const float*)d_in[4];
  const float* b1    = (const float*)d_in[5];
  const float* W2    = (const float*)d_in[6];
  const float* b2    = (const float*)d_in[7];
  float* out = (float*)d_out;

  float*  ws     = (float*)d_ws;
  float*  featsT = ws;                                    // 8*1024*256 f32
  ushort* W1f    = (ushort*)(featsT + (size_t)BS * M_PTS * C0);  // 98304 us
  ushort* W2f    = W1f + (size_t)C2 * K1DIM;              // 65536 us
  int*    idx3   = (int*)(W2f + (size_t)C2 * C2);         // 8*4096*3 i32
  float*  w3     = (float*)(idx3 + (size_t)BS * N_PTS * 3);

  dim3 tb(32, 8);
  transpose_k<<<dim3(M_PTS / 32, C0 / 32, BS), tb, 0, stream>>>(feats, featsT, C0, M_PTS);
  wprep_k<<<(C2 * K1DIM) / 256, 256, 0, stream>>>(W1, W2, W1f, W2f);
  three_nn_k<<<BS * (N_PTS / 64), 256, 0, stream>>>(xyz, pxyz, idx3, w3);
  fused_mfma_k<<<BS * (N_PTS / 64), 256, 0, stream>>>(featsT, skip, W1f, b1, W2f, b2,
                                                      idx3, w3, out);
}

// Round 3
// 61.067 us; speedup vs baseline: 4.1341x; 1.4208x over previous
//
#include <hip/hip_runtime.h>
#include <hip/hip_bf16.h>
#include <cstddef>
#include <cstdint>

#define BS    8
#define M_PTS 1024
#define N_PTS 4096
#define C0    256
#define C1    128
#define C2    256
#define K1DIM 384   // C0 + C1

typedef __attribute__((ext_vector_type(8))) short bf16x8;
typedef __attribute__((ext_vector_type(4))) float f32x4;

__device__ __forceinline__ ushort f2bf(float f) {
  union { float f; unsigned u; } v; v.f = f;
  unsigned r = v.u + 0x7fffu + ((v.u >> 16) & 1u);   // RNE
  return (ushort)(r >> 16);
}

// pfB 16B-unit index with XOR swizzle: unit (kq, n) -> kq*64 + (n ^ (kq&7)).
// Keeps B-frag reads at the balanced 8-clk floor and spreads build/h writes
// (which hold n fixed per lane-group) across all bank groups.
__device__ __forceinline__ int pfbu(int kq, int n) {
  return kq * 64 + (n ^ (kq & 7));
}

// ---------------------------------------------------------------------------
// Batched 32x32 tiled transpose: in (nb, R, C) -> out (nb, C, R)
// ---------------------------------------------------------------------------
__global__ void transpose_k(const float* __restrict__ in, float* __restrict__ out,
                            int R, int C) {
  __shared__ float tile[32][33];
  const int b  = blockIdx.z;
  const int r0 = blockIdx.y * 32, c0 = blockIdx.x * 32;
  const int tx = threadIdx.x, ty = threadIdx.y;   // 32 x 8
  const float* ip = in  + (size_t)b * R * C;
  float*       op = out + (size_t)b * R * C;
#pragma unroll
  for (int i = 0; i < 4; ++i) {
    int r = r0 + ty + i * 8, c = c0 + tx;
    if (r < R && c < C) tile[ty + i * 8][tx] = ip[(size_t)r * C + c];
  }
  __syncthreads();
#pragma unroll
  for (int i = 0; i < 4; ++i) {
    int c = c0 + ty + i * 8, r = r0 + tx;
    if (r < R && c < C) op[(size_t)c * R + r] = tile[tx][ty + i * 8];
  }
}

// ---------------------------------------------------------------------------
// Weight prep: f32 (c_out, c_in) row-major -> bf16 in MFMA A-fragment order
// [mb][kblk][g][r][e]  (m = mb*16+r, k = kblk*32+g*8+e)
// ---------------------------------------------------------------------------
__global__ __launch_bounds__(256) void wprep_k(
    const float* __restrict__ W1, const float* __restrict__ W2,
    ushort* __restrict__ W1f, ushort* __restrict__ W2f) {
  const int id = blockIdx.x * 256 + threadIdx.x;
  if (id < C2 * K1DIM) {
    int m = id / K1DIM, k = id - m * K1DIM;
    int off = (((m >> 4) * 12 + (k >> 5)) * 4 + ((k >> 3) & 3)) * 128 + (m & 15) * 8 + (k & 7);
    W1f[off] = f2bf(W1[id]);
  }
  if (id < C2 * C2) {
    int m = id >> 8, k = id & 255;
    int off = (((m >> 4) * 8 + (k >> 5)) * 4 + ((k >> 3) & 3)) * 128 + (m & 15) * 8 + (k & 7);
    W2f[off] = f2bf(W2[id]);
  }
}

// ---------------------------------------------------------------------------
// three_nn: 512 threads = 64 queries x 8 subs, each sub scans 128 points.
// Points packed {x,y,z,s2} as float4, staggered by (m>>7) so the 8 sub-streams
// land on disjoint 4-word bank groups (conflict-free ds_read_b128 broadcast).
// Exact reference arithmetic: d = (qq - 2*dot) + s2, strict-< insertion.
// ---------------------------------------------------------------------------
__global__ __launch_bounds__(512) void three_nn_k(
    const float* __restrict__ xyz, const float* __restrict__ pxyz,
    int* __restrict__ idx_o, float* __restrict__ w_o) {
  __shared__ float4 pts[1032];           // m + (m>>7)
  __shared__ float md[64][8][3];
  __shared__ int   mi[64][8][3];
  const int t  = threadIdx.x;
  const int b  = blockIdx.x >> 6;
  const int q0 = (blockIdx.x & 63) * 64;

  for (int m = t; m < M_PTS; m += 512) {
    const float x = xyz[(size_t)b * 3 * M_PTS + 3 * m + 0];
    const float y = xyz[(size_t)b * 3 * M_PTS + 3 * m + 1];
    const float z = xyz[(size_t)b * 3 * M_PTS + 3 * m + 2];
    const float s2 = __fadd_rn(__fadd_rn(__fmul_rn(x, x), __fmul_rn(y, y)),
                               __fmul_rn(z, z));
    pts[m + (m >> 7)] = (float4){x, y, z, s2};
  }
  __syncthreads();

  const int q = t >> 3, sub = t & 7;
  const int n = q0 + q;
  const float qx = pxyz[((size_t)b * N_PTS + n) * 3 + 0];
  const float qy = pxyz[((size_t)b * N_PTS + n) * 3 + 1];
  const float qz = pxyz[((size_t)b * N_PTS + n) * 3 + 2];
  const float qq = __fadd_rn(__fadd_rn(__fmul_rn(qx, qx), __fmul_rn(qy, qy)),
                             __fmul_rn(qz, qz));
  float d0 = 3.4e38f, d1 = 3.4e38f, d2 = 3.4e38f;
  int   i0 = 0, i1 = 0, i2 = 0;
  const int mbase = sub * 128;
  const int pbase = mbase + sub;
  for (int it = 0; it < 128; ++it) {
    const float4 P = pts[pbase + it];
    const float dot = __fadd_rn(__fadd_rn(__fmul_rn(qx, P.x), __fmul_rn(qy, P.y)),
                                __fmul_rn(qz, P.z));
    const float d = __fadd_rn(__fsub_rn(qq, __fmul_rn(2.0f, dot)), P.w);
    const int m = mbase + it;
    if (d < d0)      { d2 = d1; i2 = i1; d1 = d0; i1 = i0; d0 = d; i0 = m; }
    else if (d < d1) { d2 = d1; i2 = i1; d1 = d;  i1 = m; }
    else if (d < d2) { d2 = d;  i2 = m; }
  }
  md[q][sub][0] = d0; md[q][sub][1] = d1; md[q][sub][2] = d2;
  mi[q][sub][0] = i0; mi[q][sub][1] = i1; mi[q][sub][2] = i2;
  __syncthreads();

  if (sub == 0) {
    float e0 = 3.4e38f, e1 = 3.4e38f, e2 = 3.4e38f;
    int   j0 = 0, j1 = 0, j2 = 0;
#pragma unroll
    for (int s = 0; s < 8; ++s)
#pragma unroll
      for (int k = 0; k < 3; ++k) {
        float d = md[q][s][k]; int m = mi[q][s][k];
        if (d < e0)      { e2 = e1; j2 = j1; e1 = e0; j1 = j0; e0 = d; j0 = m; }
        else if (d < e1) { e2 = e1; j2 = j1; e1 = d;  j1 = m; }
        else if (d < e2) { e2 = d;  j2 = m; }
      }
    float t0 = sqrtf(fmaxf(e0, 0.f)), t1 = sqrtf(fmaxf(e1, 0.f)),
          t2 = sqrtf(fmaxf(e2, 0.f));
    float r0 = 1.0f / (t0 + 1e-8f), r1 = 1.0f / (t1 + 1e-8f),
          r2 = 1.0f / (t2 + 1e-8f);
    float rs = __fadd_rn(__fadd_rn(r0, r1), r2);
    size_t base = ((size_t)b * N_PTS + n) * 3;
    idx_o[base + 0] = j0; idx_o[base + 1] = j1; idx_o[base + 2] = j2;
    w_o[base + 0] = r0 / rs; w_o[base + 1] = r1 / rs; w_o[base + 2] = r2 / rs;
  }
}

// ---------------------------------------------------------------------------
// Fused MFMA, 512 threads / 8 waves, 64-col tile. Build phase is row-coalesced:
// wave wv interpolates queries wv*8..wv*8+7; per query, the whole wave loads
// each 1 KiB featsT row (lane l <-> channel quad 4l) fully coalesced.
// pfB uses the pfbu() XOR-swizzled fragment layout throughout.
// ---------------------------------------------------------------------------
__global__ __launch_bounds__(512) void fused_mfma_k(
    const float* __restrict__ featsT,   // (BS, M, C0) f32
    const float* __restrict__ skip,     // (BS, C1, N) f32
    const ushort* __restrict__ W1f,     // frag-order bf16
    const float* __restrict__ b1,
    const ushort* __restrict__ W2f,     // frag-order bf16
    const float* __restrict__ b2,
    const int* __restrict__ idx3, const float* __restrict__ w3,
    float* __restrict__ out) {          // (BS, C2, N) f32
  __shared__ ushort pfB[24576];         // 48 KiB: K1DIM x 64 bf16, swizzled frag order
  __shared__ int   idx_s[64][3];
  __shared__ float w_s[64][3];
  const int t  = threadIdx.x;
  const int b  = blockIdx.x & 7;            // XCD-pinned batch
  const int n0 = (blockIdx.x >> 3) * 64;

  if (t < 192) {
    int j = t / 3, kk = t - 3 * (t / 3);
    size_t gg = ((size_t)b * N_PTS + n0 + j) * 3 + kk;
    idx_s[j][kk] = idx3[gg];
    w_s[j][kk]   = w3[gg];
  }
  __syncthreads();

  const int wv = t >> 6, l = t & 63;

  // ---- rows 0..255: interpolated feats, row-coalesced gather ----
  {
    const float* fb = featsT + (size_t)b * M_PTS * C0;
#pragma unroll
    for (int qi = 0; qi < 8; ++qi) {
      const int n = wv * 8 + qi;
      const float w0 = w_s[n][0], w1 = w_s[n][1], w2 = w_s[n][2];
      const float4 f0 = *(const float4*)(fb + (size_t)idx_s[n][0] * C0 + l * 4);
      const float4 f1 = *(const float4*)(fb + (size_t)idx_s[n][1] * C0 + l * 4);
      const float4 f2 = *(const float4*)(fb + (size_t)idx_s[n][2] * C0 + l * 4);
      ushort4 hv;
      hv.x = f2bf(w0 * f0.x + w1 * f1.x + w2 * f2.x);
      hv.y = f2bf(w0 * f0.y + w1 * f1.y + w2 * f2.y);
      hv.z = f2bf(w0 * f0.z + w1 * f1.z + w2 * f2.z);
      hv.w = f2bf(w0 * f0.w + w1 * f1.w + w2 * f2.w);
      // k-quad = 4l -> kq = l>>1, in-unit offset (l&1)*4
      *reinterpret_cast<ushort4*>(&pfB[pfbu(l >> 1, n) * 8 + (l & 1) * 4]) = hv;
    }
  }
  // ---- rows 256..383: skip feats ----
#pragma unroll
  for (int it = 0; it < 8; ++it) {
    const int id = t + it * 512;
    const int r2 = id >> 6, nn = id & 63;
    const float s0v = skip[((size_t)b * C1 + 2 * r2 + 0) * N_PTS + n0 + nn];
    const float s1v = skip[((size_t)b * C1 + 2 * r2 + 1) * N_PTS + n0 + nn];
    ushort2 sv; sv.x = f2bf(s0v); sv.y = f2bf(s1v);
    const int k = C0 + 2 * r2;
    *reinterpret_cast<ushort2*>(&pfB[pfbu(k >> 3, nn) * 8 + (k & 7)]) = sv;
  }
  __syncthreads();

  const int c = l & 15, g = l >> 4;

  f32x4 acc[2][4];
#pragma unroll
  for (int i = 0; i < 2; ++i)
#pragma unroll
    for (int j = 0; j < 4; ++j) acc[i][j] = (f32x4){0.f, 0.f, 0.f, 0.f};

  // ---------------- GEMM1: h = relu(W1 @ pf + b1), K = 384 ----------------
  for (int kb = 0; kb < 12; ++kb) {
    bf16x8 bfr[4], afr[2];
#pragma unroll
    for (int j = 0; j < 4; ++j)
      bfr[j] = *reinterpret_cast<const bf16x8*>(&pfB[pfbu(kb * 4 + g, j * 16 + c) * 8]);
#pragma unroll
    for (int i = 0; i < 2; ++i)
      afr[i] = *reinterpret_cast<const bf16x8*>(&W1f[(((2 * wv + i) * 12 + kb) * 4 + g) * 128 + c * 8]);
#pragma unroll
    for (int i = 0; i < 2; ++i)
#pragma unroll
      for (int j = 0; j < 4; ++j)
        acc[i][j] = __builtin_amdgcn_mfma_f32_16x16x32_bf16(afr[i], bfr[j], acc[i][j], 0, 0, 0);
  }
  __syncthreads();                  // all pfB reads done before overwrite

  // h -> pfB (bf16, swizzled frag order); acc regs are 4 contiguous k-elems
#pragma unroll
  for (int i = 0; i < 2; ++i) {
    const int mbase = wv * 32 + i * 16 + g * 4;
    const float4 bias = *(const float4*)(b1 + mbase);
#pragma unroll
    for (int j = 0; j < 4; ++j) {
      const int n = j * 16 + c;
      ushort4 hv;
      hv.x = f2bf(fmaxf(acc[i][j].x + bias.x, 0.f));
      hv.y = f2bf(fmaxf(acc[i][j].y + bias.y, 0.f));
      hv.z = f2bf(fmaxf(acc[i][j].z + bias.z, 0.f));
      hv.w = f2bf(fmaxf(acc[i][j].w + bias.w, 0.f));
      *reinterpret_cast<ushort4*>(&pfB[pfbu(mbase >> 3, n) * 8 + (mbase & 7)]) = hv;
    }
  }
  __syncthreads();

#pragma unroll
  for (int i = 0; i < 2; ++i)
#pragma unroll
    for (int j = 0; j < 4; ++j) acc[i][j] = (f32x4){0.f, 0.f, 0.f, 0.f};

  // ---------------- GEMM2: out = relu(W2 @ h + b2), K = 256 ----------------
  for (int kb = 0; kb < 8; ++kb) {
    bf16x8 bfr[4], afr[2];
#pragma unroll
    for (int j = 0; j < 4; ++j)
      bfr[j] = *reinterpret_cast<const bf16x8*>(&pfB[pfbu(kb * 4 + g, j * 16 + c) * 8]);
#pragma unroll
    for (int i = 0; i < 2; ++i)
      afr[i] = *reinterpret_cast<const bf16x8*>(&W2f[(((2 * wv + i) * 8 + kb) * 4 + g) * 128 + c * 8]);
#pragma unroll
    for (int i = 0; i < 2; ++i)
#pragma unroll
      for (int j = 0; j < 4; ++j)
        acc[i][j] = __builtin_amdgcn_mfma_f32_16x16x32_bf16(afr[i], bfr[j], acc[i][j], 0, 0, 0);
  }

  // epilogue: relu(acc + b2) -> out (coalesced across lane%16)
#pragma unroll
  for (int i = 0; i < 2; ++i) {
    const int mbase = wv * 32 + i * 16 + g * 4;
    const float4 bias = *(const float4*)(b2 + mbase);
#pragma unroll
    for (int j = 0; j < 4; ++j) {
      const int n = n0 + j * 16 + c;
      out[((size_t)b * C2 + mbase + 0) * N_PTS + n] = fmaxf(acc[i][j].x + bias.x, 0.f);
      out[((size_t)b * C2 + mbase + 1) * N_PTS + n] = fmaxf(acc[i][j].y + bias.y, 0.f);
      out[((size_t)b * C2 + mbase + 2) * N_PTS + n] = fmaxf(acc[i][j].z + bias.z, 0.f);
      out[((size_t)b * C2 + mbase + 3) * N_PTS + n] = fmaxf(acc[i][j].w + bias.w, 0.f);
    }
  }
}

// ---------------------------------------------------------------------------
extern "C" void kernel_launch(void* const* d_in, const int* in_sizes, int n_in,
                              void* d_out, int out_size, void* d_ws, size_t ws_size,
                              hipStream_t stream) {
  const float* xyz   = (const float*)d_in[0];
  const float* pxyz  = (const float*)d_in[1];
  const float* feats = (const float*)d_in[2];
  const float* skip  = (const float*)d_in[3];
  const float* W1    = (const float*)d_in[4];
  const float* b1    = (const float*)d_in[5];
  const float* W2    = (const float*)d_in[6];
  const float* b2    = (const float*)d_in[7];
  float* out = (float*)d_out;

  float*  ws     = (float*)d_ws;
  float*  featsT = ws;                                    // 8*1024*256 f32
  ushort* W1f    = (ushort*)(featsT + (size_t)BS * M_PTS * C0);  // 98304 us
  ushort* W2f    = W1f + (size_t)C2 * K1DIM;              // 65536 us
  int*    idx3   = (int*)(W2f + (size_t)C2 * C2);         // 8*4096*3 i32
  float*  w3     = (float*)(idx3 + (size_t)BS * N_PTS * 3);

  dim3 tb(32, 8);
  transpose_k<<<dim3(M_PTS / 32, C0 / 32, BS), tb, 0, stream>>>(feats, featsT, C0, M_PTS);
  wprep_k<<<(C2 * K1DIM) / 256, 256, 0, stream>>>(W1, W2, W1f, W2f);
  three_nn_k<<<BS * (N_PTS / 64), 512, 0, stream>>>(xyz, pxyz, idx3, w3);
  fused_mfma_k<<<BS * (N_PTS / 64), 512, 0, stream>>>(featsT, skip, W1f, b1, W2f, b2,
                                                      idx3, w3, out);
}

// Round 4
// 56.595 us; speedup vs baseline: 4.4608x; 1.0790x over previous
//
#include <hip/hip_runtime.h>
#include <hip/hip_bf16.h>
#include <cstddef>
#include <cstdint>

#define BS    8
#define M_PTS 1024
#define N_PTS 4096
#define C0    256
#define C1    128
#define C2    256
#define K1DIM 384   // C0 + C1

typedef __attribute__((ext_vector_type(8))) short bf16x8;
typedef __attribute__((ext_vector_type(4))) float f32x4;

__device__ __forceinline__ ushort f2bf(float f) {
  union { float f; unsigned u; } v; v.f = f;
  unsigned r = v.u + 0x7fffu + ((v.u >> 16) & 1u);   // RNE
  return (ushort)(r >> 16);
}

// pfB 16B-unit index with XOR swizzle: unit (kq, n) -> kq*64 + (n ^ (kq&7)).
__device__ __forceinline__ int pfbu(int kq, int n) {
  return kq * 64 + (n ^ (kq & 7));
}

// ---------------------------------------------------------------------------
// Batched 32x32 tiled transpose: in (nb, R, C) -> out (nb, C, R)
// ---------------------------------------------------------------------------
__global__ void transpose_k(const float* __restrict__ in, float* __restrict__ out,
                            int R, int C) {
  __shared__ float tile[32][33];
  const int b  = blockIdx.z;
  const int r0 = blockIdx.y * 32, c0 = blockIdx.x * 32;
  const int tx = threadIdx.x, ty = threadIdx.y;   // 32 x 8
  const float* ip = in  + (size_t)b * R * C;
  float*       op = out + (size_t)b * R * C;
#pragma unroll
  for (int i = 0; i < 4; ++i) {
    int r = r0 + ty + i * 8, c = c0 + tx;
    if (r < R && c < C) tile[ty + i * 8][tx] = ip[(size_t)r * C + c];
  }
  __syncthreads();
#pragma unroll
  for (int i = 0; i < 4; ++i) {
    int c = c0 + ty + i * 8, r = r0 + tx;
    if (r < R && c < C) op[(size_t)c * R + r] = tile[tx][ty + i * 8];
  }
}

// ---------------------------------------------------------------------------
// Weight prep: f32 (c_out, c_in) row-major -> bf16 in MFMA A-fragment order
// [mb][kblk][g][r][e]  (m = mb*16+r, k = kblk*32+g*8+e)
// ---------------------------------------------------------------------------
__global__ __launch_bounds__(256) void wprep_k(
    const float* __restrict__ W1, const float* __restrict__ W2,
    ushort* __restrict__ W1f, ushort* __restrict__ W2f) {
  const int id = blockIdx.x * 256 + threadIdx.x;
  if (id < C2 * K1DIM) {
    int m = id / K1DIM, k = id - m * K1DIM;
    int off = (((m >> 4) * 12 + (k >> 5)) * 4 + ((k >> 3) & 3)) * 128 + (m & 15) * 8 + (k & 7);
    W1f[off] = f2bf(W1[id]);
  }
  if (id < C2 * C2) {
    int m = id >> 8, k = id & 255;
    int off = (((m >> 4) * 8 + (k >> 5)) * 4 + ((k >> 3) & 3)) * 128 + (m & 15) * 8 + (k & 7);
    W2f[off] = f2bf(W2[id]);
  }
}

// ---------------------------------------------------------------------------
// Fully fused: three_nn + interpolate + concat + conv1(ReLU) + conv2(ReLU)
// per 64-query tile. 512 threads / 8 waves.
//
// Wave-locality invariant: query q's 8 sub-scanners are lanes q*8..q*8+7 of
// wave q/8; its reducer (sub==0) and its build wave are the SAME wave, so the
// scan->reduce->idx_s chain needs no barriers (per-wave in-order LDS).
//
// LDS union: region A = pts(16.5K)+md(6K)+mi(6K) lives only in the nn phase;
// region B = pfB(48K) overwrites it after one barrier.
// ---------------------------------------------------------------------------
__global__ __launch_bounds__(512, 4) void fp_fused_k(
    const float* __restrict__ xyz,      // (BS, M, 3)
    const float* __restrict__ pxyz,     // (BS, N, 3)
    const float* __restrict__ featsT,   // (BS, M, C0) f32
    const float* __restrict__ skip,     // (BS, C1, N) f32
    const ushort* __restrict__ W1f,     // frag-order bf16
    const float* __restrict__ b1,
    const ushort* __restrict__ W2f,     // frag-order bf16
    const float* __restrict__ b2,
    float* __restrict__ out) {          // (BS, C2, N) f32
  __shared__ float4 smem4[3072];        // 48 KiB union
  __shared__ int   idx_s[64][3];
  __shared__ float w_s[64][3];

  float4* pts = smem4;                               // [1032] {x,y,z,s2}
  float*  md  = (float*)smem4 + 4128;                // [64][8][3]
  int*    mi  = (int*)smem4  + 4128 + 1536;          // [64][8][3]
  ushort* pfB = (ushort*)smem4;                      // [24576] frag order

  const int t  = threadIdx.x;
  const int b  = blockIdx.x & 7;            // XCD-pinned batch
  const int n0 = (blockIdx.x >> 3) * 64;

  // ---- stage reference points {x,y,z,|p|^2}, staggered by m>>7 ----
  for (int m = t; m < M_PTS; m += 512) {
    const float x = xyz[(size_t)b * 3 * M_PTS + 3 * m + 0];
    const float y = xyz[(size_t)b * 3 * M_PTS + 3 * m + 1];
    const float z = xyz[(size_t)b * 3 * M_PTS + 3 * m + 2];
    const float s2 = __fadd_rn(__fadd_rn(__fmul_rn(x, x), __fmul_rn(y, y)),
                               __fmul_rn(z, z));
    pts[m + (m >> 7)] = (float4){x, y, z, s2};
  }
  __syncthreads();

  // ---- skip prefetch into registers (consumed after the pre-build barrier;
  //      HBM latency hides under the ~15us nn scan) ----
  float skp[16];
#pragma unroll
  for (int it = 0; it < 8; ++it) {
    const int id = t + it * 512;
    const int r2 = id >> 6, nn = id & 63;
    skp[2 * it + 0] = skip[((size_t)b * C1 + 2 * r2 + 0) * N_PTS + n0 + nn];
    skp[2 * it + 1] = skip[((size_t)b * C1 + 2 * r2 + 1) * N_PTS + n0 + nn];
  }

  // ---- nn scan: 8 subs per query, 128 points each, exact ref arithmetic ----
  {
    const int q = t >> 3, sub = t & 7;
    const int gn = n0 + q;
    const float qx = pxyz[((size_t)b * N_PTS + gn) * 3 + 0];
    const float qy = pxyz[((size_t)b * N_PTS + gn) * 3 + 1];
    const float qz = pxyz[((size_t)b * N_PTS + gn) * 3 + 2];
    const float qq = __fadd_rn(__fadd_rn(__fmul_rn(qx, qx), __fmul_rn(qy, qy)),
                               __fmul_rn(qz, qz));
    float d0 = 3.4e38f, d1 = 3.4e38f, d2 = 3.4e38f;
    int   i0 = 0, i1 = 0, i2 = 0;
    const int mbase = sub * 128;
    const int pbase = mbase + sub;
    for (int it = 0; it < 128; ++it) {
      const float4 P = pts[pbase + it];
      const float dot = __fadd_rn(__fadd_rn(__fmul_rn(qx, P.x), __fmul_rn(qy, P.y)),
                                  __fmul_rn(qz, P.z));
      const float d = __fadd_rn(__fsub_rn(qq, __fmul_rn(2.0f, dot)), P.w);
      const int m = mbase + it;
      if (d < d0)      { d2 = d1; i2 = i1; d1 = d0; i1 = i0; d0 = d; i0 = m; }
      else if (d < d1) { d2 = d1; i2 = i1; d1 = d;  i1 = m; }
      else if (d < d2) { d2 = d;  i2 = m; }
    }
    // wave-local: writers and reader (sub==0) are in the same wave
    const int base = (q * 8 + sub) * 3;
    md[base + 0] = d0; md[base + 1] = d1; md[base + 2] = d2;
    mi[base + 0] = i0; mi[base + 1] = i1; mi[base + 2] = i2;

    if (sub == 0) {
      float e0 = 3.4e38f, e1 = 3.4e38f, e2 = 3.4e38f;
      int   j0 = 0, j1 = 0, j2 = 0;
#pragma unroll
      for (int s = 0; s < 8; ++s)
#pragma unroll
        for (int k = 0; k < 3; ++k) {
          float d = md[(q * 8 + s) * 3 + k]; int m = mi[(q * 8 + s) * 3 + k];
          if (d < e0)      { e2 = e1; j2 = j1; e1 = e0; j1 = j0; e0 = d; j0 = m; }
          else if (d < e1) { e2 = e1; j2 = j1; e1 = d;  j1 = m; }
          else if (d < e2) { e2 = d;  j2 = m; }
        }
      float t0 = sqrtf(fmaxf(e0, 0.f)), t1 = sqrtf(fmaxf(e1, 0.f)),
            t2 = sqrtf(fmaxf(e2, 0.f));
      float r0 = 1.0f / (t0 + 1e-8f), r1 = 1.0f / (t1 + 1e-8f),
            r2 = 1.0f / (t2 + 1e-8f);
      float rs = __fadd_rn(__fadd_rn(r0, r1), r2);
      idx_s[q][0] = j0; idx_s[q][1] = j1; idx_s[q][2] = j2;
      w_s[q][0] = r0 / rs; w_s[q][1] = r1 / rs; w_s[q][2] = r2 / rs;
    }
  }
  __syncthreads();   // pts/md/mi dead; pfB may now overwrite region A

  const int wv = t >> 6, l = t & 63;

  // ---- rows 0..255: interpolated feats, row-coalesced gather ----
  {
    const float* fb = featsT + (size_t)b * M_PTS * C0;
#pragma unroll
    for (int qi = 0; qi < 8; ++qi) {
      const int nq = wv * 8 + qi;
      const float w0 = w_s[nq][0], w1 = w_s[nq][1], w2 = w_s[nq][2];
      const float4 f0 = *(const float4*)(fb + (size_t)idx_s[nq][0] * C0 + l * 4);
      const float4 f1 = *(const float4*)(fb + (size_t)idx_s[nq][1] * C0 + l * 4);
      const float4 f2 = *(const float4*)(fb + (size_t)idx_s[nq][2] * C0 + l * 4);
      ushort4 hv;
      hv.x = f2bf(w0 * f0.x + w1 * f1.x + w2 * f2.x);
      hv.y = f2bf(w0 * f0.y + w1 * f1.y + w2 * f2.y);
      hv.z = f2bf(w0 * f0.z + w1 * f1.z + w2 * f2.z);
      hv.w = f2bf(w0 * f0.w + w1 * f1.w + w2 * f2.w);
      *reinterpret_cast<ushort4*>(&pfB[pfbu(l >> 1, nq) * 8 + (l & 1) * 4]) = hv;
    }
  }
  // ---- rows 256..383: skip feats from the prefetch registers ----
#pragma unroll
  for (int it = 0; it < 8; ++it) {
    const int id = t + it * 512;
    const int r2 = id >> 6, nn = id & 63;
    ushort2 sv; sv.x = f2bf(skp[2 * it]); sv.y = f2bf(skp[2 * it + 1]);
    const int k = C0 + 2 * r2;
    *reinterpret_cast<ushort2*>(&pfB[pfbu(k >> 3, nn) * 8 + (k & 7)]) = sv;
  }
  __syncthreads();

  const int c = l & 15, g = l >> 4;

  f32x4 acc[2][4];
#pragma unroll
  for (int i = 0; i < 2; ++i)
#pragma unroll
    for (int j = 0; j < 4; ++j) acc[i][j] = (f32x4){0.f, 0.f, 0.f, 0.f};

  // ---------------- GEMM1: h = relu(W1 @ pf + b1), K = 384 ----------------
  for (int kb = 0; kb < 12; ++kb) {
    bf16x8 bfr[4], afr[2];
#pragma unroll
    for (int j = 0; j < 4; ++j)
      bfr[j] = *reinterpret_cast<const bf16x8*>(&pfB[pfbu(kb * 4 + g, j * 16 + c) * 8]);
#pragma unroll
    for (int i = 0; i < 2; ++i)
      afr[i] = *reinterpret_cast<const bf16x8*>(&W1f[(((2 * wv + i) * 12 + kb) * 4 + g) * 128 + c * 8]);
#pragma unroll
    for (int i = 0; i < 2; ++i)
#pragma unroll
      for (int j = 0; j < 4; ++j)
        acc[i][j] = __builtin_amdgcn_mfma_f32_16x16x32_bf16(afr[i], bfr[j], acc[i][j], 0, 0, 0);
  }
  __syncthreads();                  // all pfB reads done before overwrite

  // h -> pfB (bf16, swizzled frag order)
#pragma unroll
  for (int i = 0; i < 2; ++i) {
    const int mbase = wv * 32 + i * 16 + g * 4;
    const float4 bias = *(const float4*)(b1 + mbase);
#pragma unroll
    for (int j = 0; j < 4; ++j) {
      const int nn = j * 16 + c;
      ushort4 hv;
      hv.x = f2bf(fmaxf(acc[i][j].x + bias.x, 0.f));
      hv.y = f2bf(fmaxf(acc[i][j].y + bias.y, 0.f));
      hv.z = f2bf(fmaxf(acc[i][j].z + bias.z, 0.f));
      hv.w = f2bf(fmaxf(acc[i][j].w + bias.w, 0.f));
      *reinterpret_cast<ushort4*>(&pfB[pfbu(mbase >> 3, nn) * 8 + (mbase & 7)]) = hv;
    }
  }
  __syncthreads();

#pragma unroll
  for (int i = 0; i < 2; ++i)
#pragma unroll
    for (int j = 0; j < 4; ++j) acc[i][j] = (f32x4){0.f, 0.f, 0.f, 0.f};

  // ---------------- GEMM2: out = relu(W2 @ h + b2), K = 256 ----------------
  for (int kb = 0; kb < 8; ++kb) {
    bf16x8 bfr[4], afr[2];
#pragma unroll
    for (int j = 0; j < 4; ++j)
      bfr[j] = *reinterpret_cast<const bf16x8*>(&pfB[pfbu(kb * 4 + g, j * 16 + c) * 8]);
#pragma unroll
    for (int i = 0; i < 2; ++i)
      afr[i] = *reinterpret_cast<const bf16x8*>(&W2f[(((2 * wv + i) * 8 + kb) * 4 + g) * 128 + c * 8]);
#pragma unroll
    for (int i = 0; i < 2; ++i)
#pragma unroll
      for (int j = 0; j < 4; ++j)
        acc[i][j] = __builtin_amdgcn_mfma_f32_16x16x32_bf16(afr[i], bfr[j], acc[i][j], 0, 0, 0);
  }

  // epilogue: relu(acc + b2) -> out
#pragma unroll
  for (int i = 0; i < 2; ++i) {
    const int mbase = wv * 32 + i * 16 + g * 4;
    const float4 bias = *(const float4*)(b2 + mbase);
#pragma unroll
    for (int j = 0; j < 4; ++j) {
      const int nn = n0 + j * 16 + c;
      out[((size_t)b * C2 + mbase + 0) * N_PTS + nn] = fmaxf(acc[i][j].x + bias.x, 0.f);
      out[((size_t)b * C2 + mbase + 1) * N_PTS + nn] = fmaxf(acc[i][j].y + bias.y, 0.f);
      out[((size_t)b * C2 + mbase + 2) * N_PTS + nn] = fmaxf(acc[i][j].z + bias.z, 0.f);
      out[((size_t)b * C2 + mbase + 3) * N_PTS + nn] = fmaxf(acc[i][j].w + bias.w, 0.f);
    }
  }
}

// ---------------------------------------------------------------------------
extern "C" void kernel_launch(void* const* d_in, const int* in_sizes, int n_in,
                              void* d_out, int out_size, void* d_ws, size_t ws_size,
                              hipStream_t stream) {
  const float* xyz   = (const float*)d_in[0];
  const float* pxyz  = (const float*)d_in[1];
  const float* feats = (const float*)d_in[2];
  const float* skip  = (const float*)d_in[3];
  const float* W1    = (const float*)d_in[4];
  const float* b1    = (const float*)d_in[5];
  const float* W2    = (const float*)d_in[6];
  const float* b2    = (const float*)d_in[7];
  float* out = (float*)d_out;

  float*  ws     = (float*)d_ws;
  float*  featsT = ws;                                    // 8*1024*256 f32
  ushort* W1f    = (ushort*)(featsT + (size_t)BS * M_PTS * C0);  // 98304 us
  ushort* W2f    = W1f + (size_t)C2 * K1DIM;              // 65536 us

  dim3 tb(32, 8);
  transpose_k<<<dim3(M_PTS / 32, C0 / 32, BS), tb, 0, stream>>>(feats, featsT, C0, M_PTS);
  wprep_k<<<(C2 * K1DIM) / 256, 256, 0, stream>>>(W1, W2, W1f, W2f);
  fp_fused_k<<<BS * (N_PTS / 64), 512, 0, stream>>>(xyz, pxyz, featsT, skip,
                                                    W1f, b1, W2f, b2, out);
}

// Round 5
// 50.099 us; speedup vs baseline: 5.0392x; 1.1297x over previous
//
#include <hip/hip_runtime.h>
#include <hip/hip_bf16.h>
#include <cstddef>
#include <cstdint>

#define BS    8
#define M_PTS 1024
#define N_PTS 4096
#define C0    256
#define C1    128
#define C2    256
#define K1DIM 384   // C0 + C1

typedef __attribute__((ext_vector_type(8))) short bf16x8;
typedef __attribute__((ext_vector_type(4))) float f32x4;

__device__ __forceinline__ ushort f2bf(float f) {
  union { float f; unsigned u; } v; v.f = f;
  unsigned r = v.u + 0x7fffu + ((v.u >> 16) & 1u);   // RNE
  return (ushort)(r >> 16);
}

__device__ __forceinline__ float rdlane_f(float v, int lane) {
  union { float f; int i; } u; u.f = v;
  u.i = __builtin_amdgcn_readlane(u.i, lane);
  return u.f;
}

// ---------------------------------------------------------------------------
// Merged prep: blocks [0,2048) transpose feats (BS,C0,M)->(BS,M,C0);
// blocks [2048,2432) convert W1/W2 to bf16 MFMA A-fragment order
// [mb][kblk][g][r][e]  (m = mb*16+r, k = kblk*32+g*8+e)
// ---------------------------------------------------------------------------
__global__ __launch_bounds__(256) void prep_k(
    const float* __restrict__ feats, const float* __restrict__ W1,
    const float* __restrict__ W2, float* __restrict__ featsT,
    ushort* __restrict__ W1f, ushort* __restrict__ W2f) {
  __shared__ float tile[32][33];
  const int t = threadIdx.x;
  if (blockIdx.x < 2048) {
    const int bx = blockIdx.x & 31;          // M tile
    const int by = (blockIdx.x >> 5) & 7;    // C0 tile
    const int bz = blockIdx.x >> 8;          // batch
    const int tx = t & 31, ty = t >> 5;
    const float* ip = feats + (size_t)bz * C0 * M_PTS;
    float*       op = featsT + (size_t)bz * C0 * M_PTS;
    const int r0 = by * 32, c0 = bx * 32;
#pragma unroll
    for (int i = 0; i < 4; ++i)
      tile[ty + i * 8][tx] = ip[(size_t)(r0 + ty + i * 8) * M_PTS + c0 + tx];
    __syncthreads();
#pragma unroll
    for (int i = 0; i < 4; ++i)
      op[(size_t)(c0 + ty + i * 8) * C0 + r0 + tx] = tile[tx][ty + i * 8];
  } else {
    const int id = (blockIdx.x - 2048) * 256 + t;
    if (id < C2 * K1DIM) {
      int m = id / K1DIM, k = id - m * K1DIM;
      int off = (((m >> 4) * 12 + (k >> 5)) * 4 + ((k >> 3) & 3)) * 128 + (m & 15) * 8 + (k & 7);
      W1f[off] = f2bf(W1[id]);
    }
    if (id < C2 * C2) {
      int m = id >> 8, k = id & 255;
      int off = (((m >> 4) * 8 + (k >> 5)) * 4 + ((k >> 3) & 3)) * 128 + (m & 15) * 8 + (k & 7);
      W2f[off] = f2bf(W2[id]);
    }
  }
}

// ---------------------------------------------------------------------------
// Fully fused per 32-query tile, 256 threads / 4 waves, LDS exactly 40960 B.
// scan(8 subs x 128 pts, exact fp32) -> in-reg butterfly merge -> readlane
// broadcast -> interp build (row-coalesced) -> GEMM1 -> h (old pts region)
// -> GEMM2 -> out.  Only 3 barriers; scan->build is wave-local.
// ---------------------------------------------------------------------------
__global__ __launch_bounds__(256, 4) void fp_fused_k(
    const float* __restrict__ xyz,      // (BS, M, 3)
    const float* __restrict__ pxyz,     // (BS, N, 3)
    const float* __restrict__ featsT,   // (BS, M, C0) f32
    const float* __restrict__ skip,     // (BS, C1, N) f32
    const ushort* __restrict__ W1f,
    const float* __restrict__ b1,
    const ushort* __restrict__ W2f,
    const float* __restrict__ b2,
    float* __restrict__ out) {          // (BS, C2, N) f32
  __shared__ float4 smemq[2560];                  // 40960 B total
  float4* pts4 = smemq;                           // [1024] {x,y,z,s2} XOR-swizzled
  ushort* pfB  = (ushort*)(smemq + 1024);         // [12288] 384x32 bf16 frag order
  ushort* hbuf = (ushort*)smemq;                  // [8192]  256x32 bf16 (aliases pts4)

  const int t  = threadIdx.x;
  const int b  = blockIdx.x & 7;                  // XCD-pinned batch
  const int n0 = (blockIdx.x >> 3) * 32;
  const int wv = t >> 6, l = t & 63;
  const int q  = t >> 3, sub = t & 7;

  // query coords (issued early, used in scan)
  const float qx = pxyz[((size_t)b * N_PTS + n0 + q) * 3 + 0];
  const float qy = pxyz[((size_t)b * N_PTS + n0 + q) * 3 + 1];
  const float qz = pxyz[((size_t)b * N_PTS + n0 + q) * 3 + 2];

  // stage reference points {x,y,z,|p|^2}; XOR swizzle u = m ^ ((m>>7)&7)
#pragma unroll
  for (int it = 0; it < 4; ++it) {
    const int m = t + it * 256;
    const float x = xyz[(size_t)b * 3 * M_PTS + 3 * m + 0];
    const float y = xyz[(size_t)b * 3 * M_PTS + 3 * m + 1];
    const float z = xyz[(size_t)b * 3 * M_PTS + 3 * m + 2];
    const float s2 = __fadd_rn(__fadd_rn(__fmul_rn(x, x), __fmul_rn(y, y)),
                               __fmul_rn(z, z));
    pts4[m ^ ((m >> 7) & 7)] = (float4){x, y, z, s2};
  }

  // skip prefetch into registers (HBM latency hides under the scan)
  float skp[16];
#pragma unroll
  for (int it = 0; it < 8; ++it) {
    const int id = t + it * 256;
    const int r2 = id >> 5, nn = id & 31;
    skp[2 * it + 0] = skip[((size_t)b * C1 + 2 * r2 + 0) * N_PTS + n0 + nn];
    skp[2 * it + 1] = skip[((size_t)b * C1 + 2 * r2 + 1) * N_PTS + n0 + nn];
  }

  const float qq = __fadd_rn(__fadd_rn(__fmul_rn(qx, qx), __fmul_rn(qy, qy)),
                             __fmul_rn(qz, qz));
  __syncthreads();   // barrier 1: pts staged

  // ---- scan: 8 subs x 128 pts per query, exact ref arithmetic ----
  float d0 = 3.4e38f, d1 = 3.4e38f, d2 = 3.4e38f;
  int   i0 = 0, i1 = 0, i2 = 0;
  {
    const float4* pblk = pts4 + sub * 128;
    for (int a = 0; a < 16; ++a) {
#pragma unroll
      for (int e = 0; e < 8; ++e) {
        const float4 P = pblk[(a << 3) + (e ^ sub)];
        const float dot = __fadd_rn(__fadd_rn(__fmul_rn(qx, P.x), __fmul_rn(qy, P.y)),
                                    __fmul_rn(qz, P.z));
        const float d = __fadd_rn(__fsub_rn(qq, __fmul_rn(2.0f, dot)), P.w);
        const int m = sub * 128 + (a << 3) + e;
        if (d < d0)      { d2 = d1; i2 = i1; d1 = d0; i1 = i0; d0 = d; i0 = m; }
        else if (d < d1) { d2 = d1; i2 = i1; d1 = d;  i1 = m; }
        else if (d < d2) { d2 = d;  i2 = m; }
      }
    }
  }

  // ---- in-register butterfly merge across subs (stable: lower sub wins ties)
#pragma unroll
  for (int mk = 1; mk <= 4; mk <<= 1) {
    const float pd0 = __shfl_xor(d0, mk), pd1 = __shfl_xor(d1, mk), pd2 = __shfl_xor(d2, mk);
    const int   pi0 = __shfl_xor(i0, mk), pi1 = __shfl_xor(i1, mk), pi2 = __shfl_xor(i2, mk);
    const bool lo = (sub & mk) == 0;     // my list covers the lower index range?
    const float a0 = lo ? d0 : pd0, a1 = lo ? d1 : pd1, a2 = lo ? d2 : pd2;
    const float b0 = lo ? pd0 : d0, b1v = lo ? pd1 : d1, b2v = lo ? pd2 : d2;
    const int   A0 = lo ? i0 : pi0, A1 = lo ? i1 : pi1, A2 = lo ? i2 : pi2;
    const int   B0 = lo ? pi0 : i0, B1 = lo ? pi1 : i1, B2 = lo ? pi2 : i2;
    const bool c0 = b0 < a0;             // strict: a wins ties (lower indices)
    const bool cb1a0 = b1v < a0, cb0a1 = b0 < a1;
    const bool cb1a1 = b1v < a1, cb2a0 = b2v < a0, cb0a2 = b0 < a2;
    const float m0 = c0 ? b0 : a0;                 const int M0 = c0 ? B0 : A0;
    const float t1a = cb1a0 ? b1v : a0;            const int T1a = cb1a0 ? B1 : A0;
    const float t1b = cb0a1 ? b0 : a1;             const int T1b = cb0a1 ? B0 : A1;
    const float m1 = c0 ? t1a : t1b;               const int M1 = c0 ? T1a : T1b;
    const float sA = cb2a0 ? b2v : a0;             const int SA = cb2a0 ? B2 : A0;
    const float sB = cb1a1 ? b1v : a1;             const int SB = cb1a1 ? B1 : A1;
    const float sD = cb0a2 ? b0 : a2;              const int SD = cb0a2 ? B0 : A2;
    const float m2 = c0 ? (cb1a0 ? sA : sB) : (cb0a1 ? sB : sD);
    const int   M2 = c0 ? (cb1a0 ? SA : SB) : (cb0a1 ? SB : SD);
    d0 = m0; d1 = m1; d2 = m2; i0 = M0; i1 = M1; i2 = M2;
  }

  // ---- interpolation weights (redundant on all 8 lanes of the q-group) ----
  float w0f, w1f, w2f;
  {
    const float t0 = sqrtf(fmaxf(d0, 0.f)), t1 = sqrtf(fmaxf(d1, 0.f)),
                t2 = sqrtf(fmaxf(d2, 0.f));
    const float r0 = 1.0f / (t0 + 1e-8f), r1 = 1.0f / (t1 + 1e-8f),
                r2 = 1.0f / (t2 + 1e-8f);
    const float rs = __fadd_rn(__fadd_rn(r0, r1), r2);
    w0f = r0 / rs; w1f = r1 / rs; w2f = r2 / rs;
  }

  // ---- build rows 0..255: interp feats, row-coalesced; readlane broadcast ----
  {
    const float* fb = featsT + (size_t)b * M_PTS * C0;
#pragma unroll
    for (int qi = 0; qi < 8; ++qi) {
      const int src = qi * 8;
      const int  j0 = __builtin_amdgcn_readlane(i0, src);
      const int  j1 = __builtin_amdgcn_readlane(i1, src);
      const int  j2 = __builtin_amdgcn_readlane(i2, src);
      const float w0 = rdlane_f(w0f, src), w1 = rdlane_f(w1f, src), w2 = rdlane_f(w2f, src);
      const float4 f0 = *(const float4*)(fb + (size_t)j0 * C0 + l * 4);
      const float4 f1 = *(const float4*)(fb + (size_t)j1 * C0 + l * 4);
      const float4 f2 = *(const float4*)(fb + (size_t)j2 * C0 + l * 4);
      ushort4 hv;
      hv.x = f2bf(w0 * f0.x + w1 * f1.x + w2 * f2.x);
      hv.y = f2bf(w0 * f0.y + w1 * f1.y + w2 * f2.y);
      hv.z = f2bf(w0 * f0.z + w1 * f1.z + w2 * f2.z);
      hv.w = f2bf(w0 * f0.w + w1 * f1.w + w2 * f2.w);
      const int nq = wv * 8 + qi;
      const int kq = l >> 1;
      const int u = kq * 32 + (nq ^ (kq & 7));
      *reinterpret_cast<ushort4*>(&pfB[u * 8 + (l & 1) * 4]) = hv;
    }
  }
  // ---- rows 256..383: skip feats from prefetch registers ----
#pragma unroll
  for (int it = 0; it < 8; ++it) {
    const int id = t + it * 256;
    const int r2 = id >> 5, nn = id & 31;
    const int k = C0 + 2 * r2;
    const int kq = k >> 3;
    const int u = kq * 32 + (nn ^ (kq & 7));
    ushort2 sv; sv.x = f2bf(skp[2 * it]); sv.y = f2bf(skp[2 * it + 1]);
    *reinterpret_cast<ushort2*>(&pfB[u * 8 + (k & 7)]) = sv;
  }
  __syncthreads();   // barrier 2: pfB complete

  const int c = l & 15, g = l >> 4;

  f32x4 acc[4][2];
#pragma unroll
  for (int i = 0; i < 4; ++i)
#pragma unroll
    for (int j = 0; j < 2; ++j) acc[i][j] = (f32x4){0.f, 0.f, 0.f, 0.f};

  // ---------------- GEMM1: h = relu(W1 @ pf + b1), K = 384 ----------------
  for (int kb = 0; kb < 12; ++kb) {
    const int kqg = kb * 4 + g;
    bf16x8 bfr[2], afr[4];
#pragma unroll
    for (int j = 0; j < 2; ++j)
      bfr[j] = *reinterpret_cast<const bf16x8*>(&pfB[(kqg * 32 + ((j * 16 + c) ^ (kqg & 7))) * 8]);
#pragma unroll
    for (int i = 0; i < 4; ++i)
      afr[i] = *reinterpret_cast<const bf16x8*>(&W1f[(((wv * 4 + i) * 12 + kb) * 4 + g) * 128 + c * 8]);
#pragma unroll
    for (int i = 0; i < 4; ++i)
#pragma unroll
      for (int j = 0; j < 2; ++j)
        acc[i][j] = __builtin_amdgcn_mfma_f32_16x16x32_bf16(afr[i], bfr[j], acc[i][j], 0, 0, 0);
  }

  // h -> hbuf (old pts region; no barrier needed before writes)
#pragma unroll
  for (int i = 0; i < 4; ++i) {
    const int mbase = wv * 64 + i * 16 + g * 4;
    const float4 bias = *(const float4*)(b1 + mbase);
#pragma unroll
    for (int j = 0; j < 2; ++j) {
      const int nn = j * 16 + c;
      const int kq = mbase >> 3;
      const int u = kq * 32 + (nn ^ (kq & 7));
      ushort4 hv;
      hv.x = f2bf(fmaxf(acc[i][j].x + bias.x, 0.f));
      hv.y = f2bf(fmaxf(acc[i][j].y + bias.y, 0.f));
      hv.z = f2bf(fmaxf(acc[i][j].z + bias.z, 0.f));
      hv.w = f2bf(fmaxf(acc[i][j].w + bias.w, 0.f));
      *reinterpret_cast<ushort4*>(&hbuf[u * 8 + (mbase & 7)]) = hv;
    }
  }
  __syncthreads();   // barrier 3: h complete

#pragma unroll
  for (int i = 0; i < 4; ++i)
#pragma unroll
    for (int j = 0; j < 2; ++j) acc[i][j] = (f32x4){0.f, 0.f, 0.f, 0.f};

  // ---------------- GEMM2: out = relu(W2 @ h + b2), K = 256 ----------------
  for (int kb = 0; kb < 8; ++kb) {
    const int kqg = kb * 4 + g;
    bf16x8 bfr[2], afr[4];
#pragma unroll
    for (int j = 0; j < 2; ++j)
      bfr[j] = *reinterpret_cast<const bf16x8*>(&hbuf[(kqg * 32 + ((j * 16 + c) ^ (kqg & 7))) * 8]);
#pragma unroll
    for (int i = 0; i < 4; ++i)
      afr[i] = *reinterpret_cast<const bf16x8*>(&W2f[(((wv * 4 + i) * 8 + kb) * 4 + g) * 128 + c * 8]);
#pragma unroll
    for (int i = 0; i < 4; ++i)
#pragma unroll
      for (int j = 0; j < 2; ++j)
        acc[i][j] = __builtin_amdgcn_mfma_f32_16x16x32_bf16(afr[i], bfr[j], acc[i][j], 0, 0, 0);
  }

  // epilogue: relu(acc + b2) -> out
#pragma unroll
  for (int i = 0; i < 4; ++i) {
    const int mbase = wv * 64 + i * 16 + g * 4;
    const float4 bias = *(const float4*)(b2 + mbase);
#pragma unroll
    for (int j = 0; j < 2; ++j) {
      const int nn = n0 + j * 16 + c;
      out[((size_t)b * C2 + mbase + 0) * N_PTS + nn] = fmaxf(acc[i][j].x + bias.x, 0.f);
      out[((size_t)b * C2 + mbase + 1) * N_PTS + nn] = fmaxf(acc[i][j].y + bias.y, 0.f);
      out[((size_t)b * C2 + mbase + 2) * N_PTS + nn] = fmaxf(acc[i][j].z + bias.z, 0.f);
      out[((size_t)b * C2 + mbase + 3) * N_PTS + nn] = fmaxf(acc[i][j].w + bias.w, 0.f);
    }
  }
}

// ---------------------------------------------------------------------------
extern "C" void kernel_launch(void* const* d_in, const int* in_sizes, int n_in,
                              void* d_out, int out_size, void* d_ws, size_t ws_size,
                              hipStream_t stream) {
  const float* xyz   = (const float*)d_in[0];
  const float* pxyz  = (const float*)d_in[1];
  const float* feats = (const float*)d_in[2];
  const float* skip  = (const float*)d_in[3];
  const float* W1    = (const float*)d_in[4];
  const float* b1    = (const float*)d_in[5];
  const float* W2    = (const float*)d_in[6];
  const float* b2    = (const float*)d_in[7];
  float* out = (float*)d_out;

  float*  ws     = (float*)d_ws;
  float*  featsT = ws;                                           // 8*1024*256 f32
  ushort* W1f    = (ushort*)(featsT + (size_t)BS * M_PTS * C0);  // 98304 ushort
  ushort* W2f    = W1f + (size_t)C2 * K1DIM;                     // 65536 ushort

  prep_k<<<2432, 256, 0, stream>>>(feats, W1, W2, featsT, W1f, W2f);
  fp_fused_k<<<BS * (N_PTS / 32), 256, 0, stream>>>(xyz, pxyz, featsT, skip,
                                                    W1f, b1, W2f, b2, out);
}

// Round 6
// 46.821 us; speedup vs baseline: 5.3920x; 1.0700x over previous
//
#include <hip/hip_runtime.h>
#include <hip/hip_bf16.h>
#include <cstddef>
#include <cstdint>

#define BS    8
#define M_PTS 1024
#define N_PTS 4096
#define C0    256
#define C1    128
#define C2    256
#define K1DIM 384   // C0 + C1

typedef __attribute__((ext_vector_type(8))) short bf16x8;
typedef __attribute__((ext_vector_type(4))) float f32x4;

__device__ __forceinline__ ushort f2bf(float f) {
  union { float f; unsigned u; } v; v.f = f;
  unsigned r = v.u + 0x7fffu + ((v.u >> 16) & 1u);   // RNE
  return (ushort)(r >> 16);
}

__device__ __forceinline__ float rdlane_f(float v, int lane) {
  union { float f; int i; } u; u.f = v;
  u.i = __builtin_amdgcn_readlane(u.i, lane);
  return u.f;
}

// ---------------------------------------------------------------------------
// Merged prep: blocks [0,2048) transpose feats (BS,C0,M)->(BS,M,C0);
// blocks [2048,2432) convert W1/W2 to bf16 MFMA A-fragment order
// [mb][kblk][g][r][e]  (m = mb*16+r, k = kblk*32+g*8+e)
// ---------------------------------------------------------------------------
__global__ __launch_bounds__(256) void prep_k(
    const float* __restrict__ feats, const float* __restrict__ W1,
    const float* __restrict__ W2, float* __restrict__ featsT,
    ushort* __restrict__ W1f, ushort* __restrict__ W2f) {
  __shared__ float tile[32][33];
  const int t = threadIdx.x;
  if (blockIdx.x < 2048) {
    const int bx = blockIdx.x & 31;          // M tile
    const int by = (blockIdx.x >> 5) & 7;    // C0 tile
    const int bz = blockIdx.x >> 8;          // batch
    const int tx = t & 31, ty = t >> 5;
    const float* ip = feats + (size_t)bz * C0 * M_PTS;
    float*       op = featsT + (size_t)bz * C0 * M_PTS;
    const int r0 = by * 32, c0 = bx * 32;
#pragma unroll
    for (int i = 0; i < 4; ++i)
      tile[ty + i * 8][tx] = ip[(size_t)(r0 + ty + i * 8) * M_PTS + c0 + tx];
    __syncthreads();
#pragma unroll
    for (int i = 0; i < 4; ++i)
      op[(size_t)(c0 + ty + i * 8) * C0 + r0 + tx] = tile[tx][ty + i * 8];
  } else {
    const int id = (blockIdx.x - 2048) * 256 + t;
    if (id < C2 * K1DIM) {
      int m = id / K1DIM, k = id - m * K1DIM;
      int off = (((m >> 4) * 12 + (k >> 5)) * 4 + ((k >> 3) & 3)) * 128 + (m & 15) * 8 + (k & 7);
      W1f[off] = f2bf(W1[id]);
    }
    if (id < C2 * C2) {
      int m = id >> 8, k = id & 255;
      int off = (((m >> 4) * 8 + (k >> 5)) * 4 + ((k >> 3) & 3)) * 128 + (m & 15) * 8 + (k & 7);
      W2f[off] = f2bf(W2[id]);
    }
  }
}

// ---------------------------------------------------------------------------
// Fully fused per 32-query tile, 256 threads / 4 waves, LDS 40960 B.
// Branchless scan insertion: values via v_min/v_med3 (bit-identical to the
// strict-< insertion incl. equality edges), indices via cndmask ternaries.
// ---------------------------------------------------------------------------
__global__ __launch_bounds__(256, 4) void fp_fused_k(
    const float* __restrict__ xyz,      // (BS, M, 3)
    const float* __restrict__ pxyz,     // (BS, N, 3)
    const float* __restrict__ featsT,   // (BS, M, C0) f32
    const float* __restrict__ skip,     // (BS, C1, N) f32
    const ushort* __restrict__ W1f,
    const float* __restrict__ b1,
    const ushort* __restrict__ W2f,
    const float* __restrict__ b2,
    float* __restrict__ out) {          // (BS, C2, N) f32
  __shared__ float4 smemq[2560];                  // 40960 B total
  float4* pts4 = smemq;                           // [1024] {x,y,z,s2} XOR-swizzled
  ushort* pfB  = (ushort*)(smemq + 1024);         // [12288] 384x32 bf16 frag order
  ushort* hbuf = (ushort*)smemq;                  // [8192]  256x32 bf16 (aliases pts4)

  const int t  = threadIdx.x;
  const int b  = blockIdx.x & 7;                  // XCD-pinned batch
  const int n0 = (blockIdx.x >> 3) * 32;
  const int wv = t >> 6, l = t & 63;
  const int q  = t >> 3, sub = t & 7;

  // query coords (issued early, used in scan)
  const float qx = pxyz[((size_t)b * N_PTS + n0 + q) * 3 + 0];
  const float qy = pxyz[((size_t)b * N_PTS + n0 + q) * 3 + 1];
  const float qz = pxyz[((size_t)b * N_PTS + n0 + q) * 3 + 2];

  // stage reference points {x,y,z,|p|^2}; XOR swizzle u = m ^ ((m>>7)&7)
#pragma unroll
  for (int it = 0; it < 4; ++it) {
    const int m = t + it * 256;
    const float x = xyz[(size_t)b * 3 * M_PTS + 3 * m + 0];
    const float y = xyz[(size_t)b * 3 * M_PTS + 3 * m + 1];
    const float z = xyz[(size_t)b * 3 * M_PTS + 3 * m + 2];
    const float s2 = __fadd_rn(__fadd_rn(__fmul_rn(x, x), __fmul_rn(y, y)),
                               __fmul_rn(z, z));
    pts4[m ^ ((m >> 7) & 7)] = (float4){x, y, z, s2};
  }

  // skip prefetch into registers (HBM latency hides under the scan)
  float skp[16];
#pragma unroll
  for (int it = 0; it < 8; ++it) {
    const int id = t + it * 256;
    const int r2 = id >> 5, nn = id & 31;
    skp[2 * it + 0] = skip[((size_t)b * C1 + 2 * r2 + 0) * N_PTS + n0 + nn];
    skp[2 * it + 1] = skip[((size_t)b * C1 + 2 * r2 + 1) * N_PTS + n0 + nn];
  }

  const float qq = __fadd_rn(__fadd_rn(__fmul_rn(qx, qx), __fmul_rn(qy, qy)),
                             __fmul_rn(qz, qz));
  __syncthreads();   // barrier 1: pts staged

  // ---- scan: 8 subs x 128 pts per query, exact ref arithmetic, branchless ----
  float d0 = 3.4e38f, d1 = 3.4e38f, d2 = 3.4e38f;
  int   i0 = 0, i1 = 0, i2 = 0;
  {
    const float4* pblk = pts4 + sub * 128;
    int off[8];
#pragma unroll
    for (int e = 0; e < 8; ++e) off[e] = e ^ sub;    // hoisted swizzle
    const int mbase = sub * 128;
    for (int a = 0; a < 16; ++a) {
      const int mb = mbase + (a << 3);
#pragma unroll
      for (int e = 0; e < 8; ++e) {
        const float4 P = pblk[(a << 3) + off[e]];
        const float dot = __fadd_rn(__fadd_rn(__fmul_rn(qx, P.x), __fmul_rn(qy, P.y)),
                                    __fmul_rn(qz, P.z));
        const float d = __fadd_rn(__fsub_rn(qq, __fmul_rn(2.0f, dot)), P.w);
        const int m = mb + e;
        const bool c0 = d < d0, c1 = d < d1, c2 = d < d2;
        i2 = c1 ? i1 : (c2 ? m : i2);
        i1 = c0 ? i0 : (c1 ? m : i1);
        i0 = c0 ? m : i0;
        d2 = __builtin_amdgcn_fmed3f(d, d1, d2);     // == old d2-update
        d1 = __builtin_amdgcn_fmed3f(d, d0, d1);     // == old d1-update
        d0 = fminf(d, d0);
      }
    }
  }

  // ---- in-register butterfly merge across subs (stable: lower sub wins ties)
#pragma unroll
  for (int mk = 1; mk <= 4; mk <<= 1) {
    const float pd0 = __shfl_xor(d0, mk), pd1 = __shfl_xor(d1, mk), pd2 = __shfl_xor(d2, mk);
    const int   pi0 = __shfl_xor(i0, mk), pi1 = __shfl_xor(i1, mk), pi2 = __shfl_xor(i2, mk);
    const bool lo = (sub & mk) == 0;     // my list covers the lower index range?
    const float a0 = lo ? d0 : pd0, a1 = lo ? d1 : pd1, a2 = lo ? d2 : pd2;
    const float b0 = lo ? pd0 : d0, b1v = lo ? pd1 : d1, b2v = lo ? pd2 : d2;
    const int   A0 = lo ? i0 : pi0, A1 = lo ? i1 : pi1, A2 = lo ? i2 : pi2;
    const int   B0 = lo ? pi0 : i0, B1 = lo ? pi1 : i1, B2 = lo ? pi2 : i2;
    const bool c0 = b0 < a0;             // strict: a wins ties (lower indices)
    const bool cb1a0 = b1v < a0, cb0a1 = b0 < a1;
    const bool cb1a1 = b1v < a1, cb2a0 = b2v < a0, cb0a2 = b0 < a2;
    const float m0 = c0 ? b0 : a0;                 const int M0 = c0 ? B0 : A0;
    const float t1a = cb1a0 ? b1v : a0;            const int T1a = cb1a0 ? B1 : A0;
    const float t1b = cb0a1 ? b0 : a1;             const int T1b = cb0a1 ? B0 : A1;
    const float m1 = c0 ? t1a : t1b;               const int M1 = c0 ? T1a : T1b;
    const float sA = cb2a0 ? b2v : a0;             const int SA = cb2a0 ? B2 : A0;
    const float sB = cb1a1 ? b1v : a1;             const int SB = cb1a1 ? B1 : A1;
    const float sD = cb0a2 ? b0 : a2;              const int SD = cb0a2 ? B0 : A2;
    const float m2 = c0 ? (cb1a0 ? sA : sB) : (cb0a1 ? sB : sD);
    const int   M2 = c0 ? (cb1a0 ? SA : SB) : (cb0a1 ? SB : SD);
    d0 = m0; d1 = m1; d2 = m2; i0 = M0; i1 = M1; i2 = M2;
  }

  // ---- interpolation weights (redundant on all 8 lanes of the q-group) ----
  float w0f, w1f, w2f;
  {
    const float t0 = sqrtf(fmaxf(d0, 0.f)), t1 = sqrtf(fmaxf(d1, 0.f)),
                t2 = sqrtf(fmaxf(d2, 0.f));
    const float r0 = 1.0f / (t0 + 1e-8f), r1 = 1.0f / (t1 + 1e-8f),
                r2 = 1.0f / (t2 + 1e-8f);
    const float rs = __fadd_rn(__fadd_rn(r0, r1), r2);
    w0f = r0 / rs; w1f = r1 / rs; w2f = r2 / rs;
  }

  // ---- build rows 0..255: interp feats, row-coalesced; readlane broadcast ----
  {
    const float* fb = featsT + (size_t)b * M_PTS * C0;
#pragma unroll
    for (int qi = 0; qi < 8; ++qi) {
      const int src = qi * 8;
      const int  j0 = __builtin_amdgcn_readlane(i0, src);
      const int  j1 = __builtin_amdgcn_readlane(i1, src);
      const int  j2 = __builtin_amdgcn_readlane(i2, src);
      const float w0 = rdlane_f(w0f, src), w1 = rdlane_f(w1f, src), w2 = rdlane_f(w2f, src);
      const float4 f0 = *(const float4*)(fb + (size_t)j0 * C0 + l * 4);
      const float4 f1 = *(const float4*)(fb + (size_t)j1 * C0 + l * 4);
      const float4 f2 = *(const float4*)(fb + (size_t)j2 * C0 + l * 4);
      ushort4 hv;
      hv.x = f2bf(w0 * f0.x + w1 * f1.x + w2 * f2.x);
      hv.y = f2bf(w0 * f0.y + w1 * f1.y + w2 * f2.y);
      hv.z = f2bf(w0 * f0.z + w1 * f1.z + w2 * f2.z);
      hv.w = f2bf(w0 * f0.w + w1 * f1.w + w2 * f2.w);
      const int nq = wv * 8 + qi;
      const int kq = l >> 1;
      const int u = kq * 32 + (nq ^ (kq & 7));
      *reinterpret_cast<ushort4*>(&pfB[u * 8 + (l & 1) * 4]) = hv;
    }
  }
  // ---- rows 256..383: skip feats from prefetch registers ----
#pragma unroll
  for (int it = 0; it < 8; ++it) {
    const int id = t + it * 256;
    const int r2 = id >> 5, nn = id & 31;
    const int k = C0 + 2 * r2;
    const int kq = k >> 3;
    const int u = kq * 32 + (nn ^ (kq & 7));
    ushort2 sv; sv.x = f2bf(skp[2 * it]); sv.y = f2bf(skp[2 * it + 1]);
    *reinterpret_cast<ushort2*>(&pfB[u * 8 + (k & 7)]) = sv;
  }
  __syncthreads();   // barrier 2: pfB complete

  const int c = l & 15, g = l >> 4;

  f32x4 acc[4][2];
#pragma unroll
  for (int i = 0; i < 4; ++i)
#pragma unroll
    for (int j = 0; j < 2; ++j) acc[i][j] = (f32x4){0.f, 0.f, 0.f, 0.f};

  // ---------------- GEMM1: h = relu(W1 @ pf + b1), K = 384 ----------------
  for (int kb = 0; kb < 12; ++kb) {
    const int kqg = kb * 4 + g;
    bf16x8 bfr[2], afr[4];
#pragma unroll
    for (int j = 0; j < 2; ++j)
      bfr[j] = *reinterpret_cast<const bf16x8*>(&pfB[(kqg * 32 + ((j * 16 + c) ^ (kqg & 7))) * 8]);
#pragma unroll
    for (int i = 0; i < 4; ++i)
      afr[i] = *reinterpret_cast<const bf16x8*>(&W1f[(((wv * 4 + i) * 12 + kb) * 4 + g) * 128 + c * 8]);
    __builtin_amdgcn_s_setprio(1);
#pragma unroll
    for (int i = 0; i < 4; ++i)
#pragma unroll
      for (int j = 0; j < 2; ++j)
        acc[i][j] = __builtin_amdgcn_mfma_f32_16x16x32_bf16(afr[i], bfr[j], acc[i][j], 0, 0, 0);
    __builtin_amdgcn_s_setprio(0);
  }

  // h -> hbuf (old pts region; no barrier needed before writes)
#pragma unroll
  for (int i = 0; i < 4; ++i) {
    const int mbase = wv * 64 + i * 16 + g * 4;
    const float4 bias = *(const float4*)(b1 + mbase);
#pragma unroll
    for (int j = 0; j < 2; ++j) {
      const int nn = j * 16 + c;
      const int kq = mbase >> 3;
      const int u = kq * 32 + (nn ^ (kq & 7));
      ushort4 hv;
      hv.x = f2bf(fmaxf(acc[i][j].x + bias.x, 0.f));
      hv.y = f2bf(fmaxf(acc[i][j].y + bias.y, 0.f));
      hv.z = f2bf(fmaxf(acc[i][j].z + bias.z, 0.f));
      hv.w = f2bf(fmaxf(acc[i][j].w + bias.w, 0.f));
      *reinterpret_cast<ushort4*>(&hbuf[u * 8 + (mbase & 7)]) = hv;
    }
  }
  __syncthreads();   // barrier 3: h complete

#pragma unroll
  for (int i = 0; i < 4; ++i)
#pragma unroll
    for (int j = 0; j < 2; ++j) acc[i][j] = (f32x4){0.f, 0.f, 0.f, 0.f};

  // ---------------- GEMM2: out = relu(W2 @ h + b2), K = 256 ----------------
  for (int kb = 0; kb < 8; ++kb) {
    const int kqg = kb * 4 + g;
    bf16x8 bfr[2], afr[4];
#pragma unroll
    for (int j = 0; j < 2; ++j)
      bfr[j] = *reinterpret_cast<const bf16x8*>(&hbuf[(kqg * 32 + ((j * 16 + c) ^ (kqg & 7))) * 8]);
#pragma unroll
    for (int i = 0; i < 4; ++i)
      afr[i] = *reinterpret_cast<const bf16x8*>(&W2f[(((wv * 4 + i) * 8 + kb) * 4 + g) * 128 + c * 8]);
    __builtin_amdgcn_s_setprio(1);
#pragma unroll
    for (int i = 0; i < 4; ++i)
#pragma unroll
      for (int j = 0; j < 2; ++j)
        acc[i][j] = __builtin_amdgcn_mfma_f32_16x16x32_bf16(afr[i], bfr[j], acc[i][j], 0, 0, 0);
    __builtin_amdgcn_s_setprio(0);
  }

  // epilogue: relu(acc + b2) -> out
#pragma unroll
  for (int i = 0; i < 4; ++i) {
    const int mbase = wv * 64 + i * 16 + g * 4;
    const float4 bias = *(const float4*)(b2 + mbase);
#pragma unroll
    for (int j = 0; j < 2; ++j) {
      const int nn = n0 + j * 16 + c;
      out[((size_t)b * C2 + mbase + 0) * N_PTS + nn] = fmaxf(acc[i][j].x + bias.x, 0.f);
      out[((size_t)b * C2 + mbase + 1) * N_PTS + nn] = fmaxf(acc[i][j].y + bias.y, 0.f);
      out[((size_t)b * C2 + mbase + 2) * N_PTS + nn] = fmaxf(acc[i][j].z + bias.z, 0.f);
      out[((size_t)b * C2 + mbase + 3) * N_PTS + nn] = fmaxf(acc[i][j].w + bias.w, 0.f);
    }
  }
}

// ---------------------------------------------------------------------------
extern "C" void kernel_launch(void* const* d_in, const int* in_sizes, int n_in,
                              void* d_out, int out_size, void* d_ws, size_t ws_size,
                              hipStream_t stream) {
  const float* xyz   = (const float*)d_in[0];
  const float* pxyz  = (const float*)d_in[1];
  const float* feats = (const float*)d_in[2];
  const float* skip  = (const float*)d_in[3];
  const float* W1    = (const float*)d_in[4];
  const float* b1    = (const float*)d_in[5];
  const float* W2    = (const float*)d_in[6];
  const float* b2    = (const float*)d_in[7];
  float* out = (float*)d_out;

  float*  ws     = (float*)d_ws;
  float*  featsT = ws;                                           // 8*1024*256 f32
  ushort* W1f    = (ushort*)(featsT + (size_t)BS * M_PTS * C0);  // 98304 ushort
  ushort* W2f    = W1f + (size_t)C2 * K1DIM;                     // 65536 ushort

  prep_k<<<2432, 256, 0, stream>>>(feats, W1, W2, featsT, W1f, W2f);
  fp_fused_k<<<BS * (N_PTS / 32), 256, 0, stream>>>(xyz, pxyz, featsT, skip,
                                                    W1f, b1, W2f, b2, out);
}